// Round 5
// baseline (360.162 us; speedup 1.0000x reference)
//
#include <hip/hip_runtime.h>
#include <hip/hip_bf16.h>

typedef __attribute__((ext_vector_type(8))) short short8;
typedef __attribute__((ext_vector_type(4))) short short4v;
typedef __attribute__((ext_vector_type(4))) float floatx4;

#define DI __device__ __forceinline__

// Problem constants
constexpr int B_ = 2, N_ = 2048, H_ = 16, DK_ = 128, DV_ = 128, E_ = 2048;
constexpr int M_ = B_ * N_;          // 4096 token rows
constexpr int NCAT_ = 4 * E_;        // 8192 = q|k|v|g concat
constexpr int CH_ = 128;             // chunk length
constexpr int NC_ = N_ / CH_;        // 16 chunks
constexpr float KSCALE = 0.08838834764831845f; // 1/sqrt(128)

// Workspace layout (bytes)
constexpr long OFF_XB   = 0;                    // 16MB  bf16 x      (reused as RG after GEMM1)
constexpr long OFF_WCAT = 16777216;             // 32MB  bf16 Wq|Wk|Wv|Wg  (reused as MS f32 after GEMM1)
constexpr long OFF_WOB  = 50331648;             // 8MB   bf16 Wo
constexpr long OFF_BCAT = 58720256;             // 32KB  f32 concat bias
constexpr long OFF_Y    = 58753024;             // 64MB  bf16 [4096][8192] q|k|v|silu(g)
constexpr long OFF_KT   = 125861888;            // 16MB  bf16 Ktd [b][h][dk][t]  (k * dec^-(t%128))
constexpr long OFF_VT   = 142639104;            // 16MB  bf16 Vt  [b][h][dv][t]
constexpr long OFF_SCB  = 159416320;            // 16MB  bf16 per-chunk start states [bh][c][dv][dk]

DI unsigned short f2bf(float f){
  unsigned u = __float_as_uint(f);
  u += 0x7fffu + ((u >> 16) & 1u);
  return (unsigned short)(u >> 16);
}
DI float bf2f(unsigned short s){ return __uint_as_float(((unsigned)s) << 16); }

DI void gload_lds16(const void* g, void* l){
  __builtin_amdgcn_global_load_lds(
      (const __attribute__((address_space(1))) unsigned int*)g,
      (__attribute__((address_space(3))) unsigned int*)l, 16, 0, 0);
}

// ---------------- fused prep: all f32->bf16 casts + bias concat ----------------
// blocks [0,4096): x ; [4096,6144): Wq ; [6144,8192): Wk ; [8192,10240): Wv ;
// [10240,12288): Wg ; [12288,14336): Wo ; [14336,14340): bias concat
__global__ void k_castall(const float* __restrict__ x,
                          const float* __restrict__ Wq, const float* __restrict__ Wk,
                          const float* __restrict__ Wv, const float* __restrict__ Wg,
                          const float* __restrict__ Wo,
                          const float* __restrict__ bq, const float* __restrict__ bk,
                          const float* __restrict__ bv, const float* __restrict__ bg,
                          unsigned short* __restrict__ xb, unsigned short* __restrict__ Wcat,
                          unsigned short* __restrict__ Wob, float* __restrict__ bcat){
  int bid = blockIdx.x;
  if(bid >= 14336){
    int i = (bid - 14336) * 2048 + threadIdx.x * 8;
    #pragma unroll
    for(int u=0;u<8;++u){
      int j = i + u;
      float v;
      if(j < 2048)      v = bq[j];
      else if(j < 4096) v = bk[j - 2048];
      else if(j < 6144) v = bv[j - 4096];
      else              v = bg[j - 6144];
      bcat[j] = v;
    }
    return;
  }
  const float* s; unsigned short* d; long off;
  if(bid < 4096){ s = x; d = xb; off = (long)bid*2048; }
  else if(bid < 6144){ s = Wq; d = Wcat;            off = (long)(bid-4096)*2048; }
  else if(bid < 8192){ s = Wk; d = Wcat + 4194304L; off = (long)(bid-6144)*2048; }
  else if(bid < 10240){ s = Wv; d = Wcat + 8388608L; off = (long)(bid-8192)*2048; }
  else if(bid < 12288){ s = Wg; d = Wcat + 12582912L; off = (long)(bid-10240)*2048; }
  else { s = Wo; d = Wob; off = (long)(bid-12288)*2048; }
  long i = off + (long)threadIdx.x * 8;
  float4 v0 = *(const float4*)(s + i);
  float4 v1 = *(const float4*)(s + i + 4);
  short8 o;
  o[0]=(short)f2bf(v0.x); o[1]=(short)f2bf(v0.y); o[2]=(short)f2bf(v0.z); o[3]=(short)f2bf(v0.w);
  o[4]=(short)f2bf(v1.x); o[5]=(short)f2bf(v1.y); o[6]=(short)f2bf(v1.z); o[7]=(short)f2bf(v1.w);
  *(short8*)(d + i) = o;
}

// ================= 256x256 GEMM, A staged in LDS / B direct-to-registers =================
// 512 threads = 8 waves (2M x 4N), wave tile 128x64, BK=64. A-tile (256x64=32KB,
// 4-way wave-shared) double-buffered in LDS with XOR chunk swizzle; B-frags
// (2-way shared) loaded straight from global/L2 into 8xshort8 regs per tile.
// LDS read traffic/tile: 128KB (A only) ~ 1550cy < MFMA 2480cy -> MFMA-bound.
// One __syncthreads per K-tile drains the A-staging gloads (issued a tile ago).
__global__ __launch_bounds__(512, 2)
void k_gemm256(const unsigned short* __restrict__ A,
               const unsigned short* __restrict__ Bt,
               unsigned short* __restrict__ Y,
               const float* __restrict__ bias)
{
  extern __shared__ unsigned short lds[];   // 2 buf x 16384 shorts (A tiles)
  constexpr int K = 2048;
  constexpr int NKT = K / 64;               // 32

  const int tid = threadIdx.x;
  const int wave = tid >> 6, lane = tid & 63;
  const int wr = wave >> 2, wc = wave & 3;
  const int l15 = lane & 15;

  // XCD-bijective 8x8 supertile swizzle
  int bid = blockIdx.x;
  int g = bid & 7, w = bid >> 3;
  int bm = (g & 1) * 8 + (w & 7);           // 0..15
  int bn = (g >> 1) * 8 + (w >> 3);         // 0..31

  const unsigned short* Ab = A  + (long)bm * 256 * K;

  // ---- A staging geometry: 32 gloads of 1KB per tile; wave handles i = wave*4+s ----
  // gload i, lane L: dst short = i*512 + L*8 (row i*8+(L>>3), pos L&7);
  // stored pos p holds logical chunk c = p ^ (row&7)  ->  src col elems = ((L&7)^(L>>3))*8
  const int sr = (lane >> 3);                       // 0..7 row-within-gload
  const int sc = ((lane & 7) ^ sr) * 8;             // source col elems
  // ---- A read geometry: frag ai rows wr*128+ai*16+l15; chunk c = kk*4+(lane>>4);
  // byte = row*128 + (c ^ (lane&7))*16
  int rbA[8];
  #pragma unroll
  for(int ai=0;ai<8;++ai) rbA[ai] = (wr*128 + ai*16 + l15) << 7;
  const int colx[2] = { ((0 + (lane>>4)) ^ (lane&7)) << 4,
                        ((4 + (lane>>4)) ^ (lane&7)) << 4 };

  // ---- B direct-load base: frag bj, kk: row = bn*256+wc*64+bj*16+l15, col = kt*64+kk*32+(lane>>4)*8
  const unsigned short* Bp = Bt + (long)(bn*256 + wc*64 + l15) * K + ((lane >> 4) << 3);

  floatx4 acc[8][4] = {};
  const char* ldsc = (const char*)lds;

#define STG_A(buf, kt) do{                                                            \
    _Pragma("unroll")                                                                 \
    for(int s=0;s<4;++s){                                                             \
      const int _i = wave*4 + s;                                                      \
      gload_lds16(Ab + (long)(_i*8 + sr)*K + (long)(kt)*64 + sc,                      \
                  &lds[(buf)*16384 + _i*512 + lane*8]);                               \
    }                                                                                 \
  }while(0)

  STG_A(0, 0);   // prologue

  for(int u=0; u<NKT; ++u){
    const int cur = u & 1, nxt = cur ^ 1;
    const int ktn = (u + 1) & (NKT - 1);

    __syncthreads();              // A(cur) ready (staged a full tile ago)
    STG_A(nxt, ktn);              // stage next A tile

    // B frags for this tile -> registers (L2-served, 2-way wave-shared)
    short8 b0[4], b1[4];
    {
      const unsigned short* Bk = Bp + (long)u * 64;
      #pragma unroll
      for(int bj=0;bj<4;++bj){
        b0[bj] = *(const short8*)(Bk + (long)bj*16*K);
        b1[bj] = *(const short8*)(Bk + (long)bj*16*K + 32);
      }
    }

    const char* cA = ldsc + cur*32768;
    #pragma unroll
    for(int kk=0;kk<2;++kk){
      short8 a8[8];
      #pragma unroll
      for(int ai=0;ai<8;++ai) a8[ai] = *(const short8*)(cA + rbA[ai] + colx[kk]);
      #pragma unroll
      for(int ai=0;ai<8;++ai)
        #pragma unroll
        for(int bj=0;bj<4;++bj)
          acc[ai][bj] = __builtin_amdgcn_mfma_f32_16x16x32_bf16(
              a8[ai], kk ? b1[bj] : b0[bj], acc[ai][bj], 0,0,0);
    }
  }
#undef STG_A

  // epilogue: bias + section transforms, bf16 store
  #pragma unroll
  for(int ai=0;ai<8;++ai){
    const int rowi = bm*256 + wr*128 + ai*16 + ((lane>>4)<<2);
    #pragma unroll
    for(int bj=0;bj<4;++bj){
      const int col = bn*256 + wc*64 + bj*16 + l15;
      const float bs = bias[col];
      const int sec = col >> 11;
      #pragma unroll
      for(int r=0;r<4;++r){
        float v = acc[ai][bj][r] + bs;
        if(sec == 1) v *= KSCALE;
        else if(sec == 3) v = v / (1.f + __expf(-v));   // silu
        Y[(long)(rowi + r) * NCAT_ + col] = f2bf(v);
      }
    }
  }
}

// ---------------- 128^2 GEMM, flat-pipelined double-buffer (output projection) ----------------
template<int EPI>
__global__ __launch_bounds__(256)
void k_gemm(const unsigned short* __restrict__ A,
            const unsigned short* __restrict__ Bt,
            void* __restrict__ outp,
            const float* __restrict__ bias,
            int M, int Ncols, int K, int NB)
{
  __shared__ unsigned short lA[2*128*64];
  __shared__ unsigned short lB[2*128*64];
  const int bid = blockIdx.x;
  const int bm = bid / NB, bn = bid % NB;
  const int tid = threadIdx.x;
  const int wave = tid >> 6, lane = tid & 63;
  const int wr = wave >> 1, wc = wave & 1;

  floatx4 acc[4][4] = {};

  int srow[4], scol[4];
  #pragma unroll
  for(int is=0; is<4; ++is){
    int o = is*4096 + wave*1024 + lane*16;     // byte offset in 16KB tile
    int row = o >> 7;
    int logcb = (o & 127) ^ ((row & 7) << 4);  // inverse-swizzled source column
    srow[is] = row; scol[is] = logcb >> 1;
  }
  const unsigned short* Abase = A + (long)bm * 128 * K;
  const unsigned short* Bbase = Bt + (long)bn * 128 * K;

#define STG128(kt, buf) do{                                                          \
    const int _k0 = (kt) << 6;                                                       \
    _Pragma("unroll")                                                                \
    for(int is=0; is<4; ++is){                                                       \
      gload_lds16(Abase + (long)srow[is]*K + _k0 + scol[is], &lA[(buf)*8192 + ((is*4096 + wave*1024) >> 1)]); \
      gload_lds16(Bbase + (long)srow[is]*K + _k0 + scol[is], &lB[(buf)*8192 + ((is*4096 + wave*1024) >> 1)]); \
    }                                                                                \
  }while(0)

  const int nkt = K >> 6;
  STG128(0, 0);
  for(int kt=0; kt<nkt; ++kt){
    const int cur = kt & 1, nxt = cur ^ 1;
    const int ktn = (kt + 1 == nkt) ? 0 : kt + 1;
    __syncthreads();
    STG128(ktn, nxt);
    const char* cA = (const char*)lA + cur*16384;
    const char* cB = (const char*)lB + cur*16384;
    #pragma unroll
    for(int kk=0; kk<2; ++kk){
      const int cb = (kk<<6) + ((lane>>4)<<4);
      short8 af[4], bfr[4];
      #pragma unroll
      for(int i=0;i<4;++i){
        int row = (wr<<6) + (i<<4) + (lane&15);
        af[i] = *(const short8*)(cA + (row<<7) + (cb ^ ((row&7)<<4)));
      }
      #pragma unroll
      for(int j=0;j<4;++j){
        int row = (wc<<6) + (j<<4) + (lane&15);
        bfr[j] = *(const short8*)(cB + (row<<7) + (cb ^ ((row&7)<<4)));
      }
      #pragma unroll
      for(int i=0;i<4;++i)
        #pragma unroll
        for(int j=0;j<4;++j)
          acc[i][j] = __builtin_amdgcn_mfma_f32_16x16x32_bf16(af[i], bfr[j], acc[i][j], 0,0,0);
    }
  }
#undef STG128

  #pragma unroll
  for(int i=0;i<4;++i){
    #pragma unroll
    for(int j=0;j<4;++j){
      #pragma unroll
      for(int r=0;r<4;++r){
        int row = bm*128 + (wr<<6) + (i<<4) + ((lane>>4)<<2) + r;
        int col = bn*128 + (wc<<6) + (j<<4) + (lane&15);
        float v = acc[i][j][r] + bias[col];
        if(EPI == 0){
          int sec = col >> 11;
          if(sec == 1) v *= KSCALE;
          else if(sec == 3) v = v / (1.f + __expf(-v));   // silu
          ((unsigned short*)outp)[(long)row * Ncols + col] = f2bf(v);
        } else {
          ((float*)outp)[(long)row * Ncols + col] = v;
        }
      }
    }
  }
}

// ---------------- transpose K,V to t-contiguous; bake dec^-(t%128) into K ----------------
__global__ __launch_bounds__(256)
void k_transpose(const unsigned short* __restrict__ Y,
                 unsigned short* __restrict__ Kt, unsigned short* __restrict__ Vt){
  __shared__ unsigned short lt[128][136];
  int bid = blockIdx.x;
  int op = bid >> 9;            // 0: K, 1: V
  int r  = bid & 511;
  int bh = r >> 4, c = r & 15, b = bh >> 4, h = bh & 15;
  int tid = threadIdx.x;
  float dec = 1.f - exp2f(-5.f - (float)h);
  float l2d = log2f(dec);
  int sec = op ? 4096 : 2048;
  unsigned short* Dst = op ? Vt : Kt;

  #pragma unroll
  for(int p=0;p<8;++p){
    int t = p*16 + (tid>>4);
    long src = ((long)(b*N_ + c*CH_ + t)) * NCAT_ + sec + h*128 + (tid&15)*8;
    short8 v = *(const short8*)(Y + src);
    if(op == 0){
      float f = exp2f(-(float)t * l2d);   // dec^{-t}
      #pragma unroll
      for(int u=0;u<8;++u) v[u] = (short)f2bf(bf2f((unsigned short)v[u]) * f);
    }
    *(short8*)&lt[t][(tid&15)*8] = v;
  }
  __syncthreads();
  #pragma unroll
  for(int p=0;p<8;++p){
    int dk = p*16 + (tid>>4);
    int tc = (tid&15)*8;
    short8 o;
    #pragma unroll
    for(int u=0;u<8;++u) o[u] = (short)lt[tc+u][dk];
    *(short8*)(Dst + ((long)(bh*128 + dk)) * N_ + c*CH_ + tc) = o;
  }
}

// ---------------- per-chunk summary Mt_c[dv][dk] = dec^{C-1} * sum_t Vt[dv][t]*Ktd[dk][t] ----------------
__global__ __launch_bounds__(256)
void k_chunksum(const unsigned short* __restrict__ Ktd, const unsigned short* __restrict__ Vt,
                float* __restrict__ MS){
  int bid = blockIdx.x;            // 512: bh*16 + c
  int bh = bid >> 4, c = bid & 15, h = bh & 15;
  int tid = threadIdx.x, wave = tid >> 6, lane = tid & 63;
  int wr = wave >> 1, wc = wave & 1;
  floatx4 acc[4][4] = {};
  const unsigned short* Vb = Vt  + (long)bh*128*N_ + c*CH_;
  const unsigned short* Kb = Ktd + (long)bh*128*N_ + c*CH_;

  #pragma unroll
  for(int kk=0;kk<4;++kk){
    int tl = kk*32 + ((lane>>4)<<3);
    short8 af[4], bfr[4];
    #pragma unroll
    for(int i=0;i<4;++i){ int dv = (wr<<6)+(i<<4)+(lane&15); af[i]  = *(const short8*)(Vb + (long)dv*N_ + tl); }
    #pragma unroll
    for(int j=0;j<4;++j){ int dk = (wc<<6)+(j<<4)+(lane&15); bfr[j] = *(const short8*)(Kb + (long)dk*N_ + tl); }
    #pragma unroll
    for(int i=0;i<4;++i)
      #pragma unroll
      for(int j=0;j<4;++j)
        acc[i][j] = __builtin_amdgcn_mfma_f32_16x16x32_bf16(af[i], bfr[j], acc[i][j], 0,0,0);
  }
  float dec = 1.f - exp2f(-5.f - (float)h);
  float scale = exp2f(127.f * log2f(dec));    // dec^{C-1}
  float* Mo = MS + ((long)bh*NC_ + c) * 16384;
  #pragma unroll
  for(int i=0;i<4;++i)
    #pragma unroll
    for(int j=0;j<4;++j)
      #pragma unroll
      for(int r=0;r<4;++r){
        int dv = (wr<<6)+(i<<4)+((lane>>4)<<2)+r;
        int dk = (wc<<6)+(j<<4)+(lane&15);
        Mo[dv*128 + dk] = acc[i][j][r] * scale;
      }
}

// ---------------- parallel scan over chunks (elementwise over state entries) ----------------
__global__ __launch_bounds__(256)
void k_scan(const float* __restrict__ MS, unsigned short* __restrict__ Scb,
            float* __restrict__ stateOut){
  int bid = blockIdx.x;
  int bh = bid >> 4, p = bid & 15;
  int tid = threadIdx.x, h = bh & 15;
  float dec = 1.f - exp2f(-5.f - (float)h);
  float decC = exp2f(128.f * log2f(dec));     // dec^C
  int e0 = p*1024 + tid*4;
  floatx4 S = {0.f, 0.f, 0.f, 0.f};
  const float* base = MS + (long)bh * NC_ * 16384 + e0;
  unsigned short* sb = Scb + (long)bh * NC_ * 16384 + e0;
  for(int c=0;c<NC_;++c){
    floatx4 m = *(const floatx4*)(base + (long)c*16384);
    short4v q;
    #pragma unroll
    for(int u=0;u<4;++u) q[u] = (short)f2bf(S[u]);
    *(short4v*)(sb + (long)c*16384) = q;
    S = decC * S + m;
  }
  // final state: element e = dv*128+dk (transposed layout) -> out [b][h][dk][dv]
  int dv = e0 >> 7, dk = e0 & 127;
  float* so = stateOut + (long)bh*16384 + dv;
  #pragma unroll
  for(int u=0;u<4;++u) so[(long)(dk+u)*128] = S[u];
}

// ---------------- retention output: masked decayed QK^T @ V + cross, group-norm, gate ----------------
__global__ __launch_bounds__(256)
void k_ret(const unsigned short* __restrict__ Y, const unsigned short* __restrict__ Vt,
           const unsigned short* __restrict__ Scb, unsigned short* __restrict__ RG){
  __shared__ unsigned short sQ[128*128];   // Qd = q * dec^t   (swizzled)
  __shared__ unsigned short sK[128*128];   // Kd = k * dec^-s ; reused for P
  int bid = blockIdx.x;
  int bh = bid >> 4, c = bid & 15, b = bh >> 4, h = bh & 15;
  int tid = threadIdx.x, w = tid >> 6, lane = tid & 63;
  float dec = 1.f - exp2f(-5.f - (float)h);
  float l2d = log2f(dec);

  #pragma unroll
  for(int p=0;p<8;++p){
    int t = p*16 + (tid>>4);
    long row = (long)(b*N_ + c*CH_ + t) * NCAT_ + h*128 + (tid&15)*8;
    short8 qv = *(const short8*)(Y + row);          // q section
    short8 kv = *(const short8*)(Y + row + 2048);   // k section
    float fq = exp2f((float)t * l2d);
    float fk = exp2f(-(float)t * l2d);
    short8 qs, ks;
    #pragma unroll
    for(int u=0;u<8;++u){
      qs[u] = (short)f2bf(bf2f((unsigned short)qv[u]) * fq);
      ks[u] = (short)f2bf(bf2f((unsigned short)kv[u]) * fk);
    }
    int ad = t*256 + (((tid&15)*16) ^ ((t&7)<<4));
    *(short8*)((char*)sQ + ad) = qs;
    *(short8*)((char*)sK + ad) = ks;
  }
  __syncthreads();

  floatx4 acc[2][8] = {};
  // QK^T (already includes dec^{t-s})
  #pragma unroll
  for(int kk=0;kk<4;++kk){
    int cb = (kk<<6) + ((lane>>4)<<4);
    short8 af[2], bfr[8];
    #pragma unroll
    for(int i=0;i<2;++i){ int t = w*32 + (i<<4) + (lane&15); af[i] = *(const short8*)((const char*)sQ + t*256 + (cb ^ ((t&7)<<4))); }
    #pragma unroll
    for(int j=0;j<8;++j){ int s = (j<<4) + (lane&15); bfr[j] = *(const short8*)((const char*)sK + s*256 + (cb ^ ((s&7)<<4))); }
    #pragma unroll
    for(int i=0;i<2;++i)
      #pragma unroll
      for(int j=0;j<8;++j)
        acc[i][j] = __builtin_amdgcn_mfma_f32_16x16x32_bf16(af[i], bfr[j], acc[i][j], 0,0,0);
  }
  __syncthreads();   // all waves done reading sK

  // causal mask, write P (bf16) into sK
  #pragma unroll
  for(int i=0;i<2;++i)
    #pragma unroll
    for(int j=0;j<8;++j)
      #pragma unroll
      for(int r=0;r<4;++r){
        int t = w*32 + (i<<4) + ((lane>>4)<<2) + r;
        int s = (j<<4) + (lane&15);
        float v = (s <= t) ? acc[i][j][r] : 0.f;
        *(unsigned short*)((char*)sK + t*256 + ((s*2) ^ ((t&7)<<4))) = f2bf(v);
      }
  __syncthreads();

  #pragma unroll
  for(int i=0;i<2;++i)
    #pragma unroll
    for(int j=0;j<8;++j)
      #pragma unroll
      for(int u=0;u<4;++u) acc[i][j][u] = 0.f;

  // ret = P @ V
  const unsigned short* Vb = Vt + (long)bh*128*N_ + c*CH_;
  #pragma unroll
  for(int kk=0;kk<4;++kk){
    int cb = (kk<<6) + ((lane>>4)<<4);
    int sg = kk*32 + ((lane>>4)<<3);
    short8 af[2], bfr[8];
    #pragma unroll
    for(int i=0;i<2;++i){ int t = w*32 + (i<<4) + (lane&15); af[i] = *(const short8*)((const char*)sK + t*256 + (cb ^ ((t&7)<<4))); }
    #pragma unroll
    for(int j=0;j<8;++j){ int dv = (j<<4) + (lane&15); bfr[j] = *(const short8*)(Vb + (long)dv*N_ + sg); }
    #pragma unroll
    for(int i=0;i<2;++i)
      #pragma unroll
      for(int j=0;j<8;++j)
        acc[i][j] = __builtin_amdgcn_mfma_f32_16x16x32_bf16(af[i], bfr[j], acc[i][j], 0,0,0);
  }
  // + dec^{t+1} * q @ S_c   (A = Qd*dec, B = Scb[dv][dk])
  const unsigned short* Sb = Scb + ((long)bh*NC_ + c) * 16384;
  #pragma unroll
  for(int kk=0;kk<4;++kk){
    int cb = (kk<<6) + ((lane>>4)<<4);
    int kg = kk*32 + ((lane>>4)<<3);
    short8 af[2], bfr[8];
    #pragma unroll
    for(int i=0;i<2;++i){
      int t = w*32 + (i<<4) + (lane&15);
      short8 qv = *(const short8*)((const char*)sQ + t*256 + (cb ^ ((t&7)<<4)));
      #pragma unroll
      for(int u=0;u<8;++u) af[i][u] = (short)f2bf(bf2f((unsigned short)qv[u]) * dec);
    }
    #pragma unroll
    for(int j=0;j<8;++j){ int dv = (j<<4) + (lane&15); bfr[j] = *(const short8*)(Sb + (long)dv*128 + kg); }
    #pragma unroll
    for(int i=0;i<2;++i)
      #pragma unroll
      for(int j=0;j<8;++j)
        acc[i][j] = __builtin_amdgcn_mfma_f32_16x16x32_bf16(af[i], bfr[j], acc[i][j], 0,0,0);
  }

  // group-norm over DV per row, gate, write bf16
  #pragma unroll
  for(int i=0;i<2;++i){
    #pragma unroll
    for(int r=0;r<4;++r){
      float s1 = 0.f, s2 = 0.f;
      #pragma unroll
      for(int j=0;j<8;++j){ float v = acc[i][j][r]; s1 += v; s2 += v*v; }
      #pragma unroll
      for(int off=1; off<16; off<<=1){ s1 += __shfl_xor(s1, off); s2 += __shfl_xor(s2, off); }
      float mu  = s1 * (1.f/128.f);
      float var = s2 * (1.f/128.f) - mu*mu;
      float inv = rsqrtf(var + 1e-6f);
      int t = w*32 + (i<<4) + ((lane>>4)<<2) + r;
      long mrow = (long)(b*N_ + c*CH_ + t);
      #pragma unroll
      for(int j=0;j<8;++j){
        int dv = (j<<4) + (lane&15);
        float v = (acc[i][j][r] - mu) * inv;
        float g = bf2f(Y[mrow*NCAT_ + 6144 + h*128 + dv]);
        RG[mrow*E_ + h*128 + dv] = f2bf(v * g);
      }
    }
  }
}

// ---------------- launch ----------------
extern "C" void kernel_launch(void* const* d_in, const int* in_sizes, int n_in,
                              void* d_out, int out_size, void* d_ws, size_t ws_size,
                              hipStream_t stream) {
  const float* x  = (const float*)d_in[0];
  const float* Wq = (const float*)d_in[1];
  const float* bq = (const float*)d_in[2];
  const float* Wk = (const float*)d_in[3];
  const float* bk = (const float*)d_in[4];
  const float* Wv = (const float*)d_in[5];
  const float* bv = (const float*)d_in[6];
  const float* Wg = (const float*)d_in[7];
  const float* bg = (const float*)d_in[8];
  const float* Wo = (const float*)d_in[9];
  const float* bo = (const float*)d_in[10];

  char* ws = (char*)d_ws;
  unsigned short* xb   = (unsigned short*)(ws + OFF_XB);
  unsigned short* Wcat = (unsigned short*)(ws + OFF_WCAT);
  unsigned short* Wob  = (unsigned short*)(ws + OFF_WOB);
  float*          bcat = (float*)(ws + OFF_BCAT);
  unsigned short* Y    = (unsigned short*)(ws + OFF_Y);
  unsigned short* Ktd  = (unsigned short*)(ws + OFF_KT);
  unsigned short* Vt   = (unsigned short*)(ws + OFF_VT);
  unsigned short* Scb  = (unsigned short*)(ws + OFF_SCB);
  float*          MS   = (float*)(ws + OFF_WCAT);   // reuse after GEMM1
  unsigned short* RG   = (unsigned short*)(ws + OFF_XB); // reuse after GEMM1

  float* outp     = (float*)d_out;
  float* stateOut = outp + (long)M_ * E_;   // 8,388,608

  // allow 64KB dynamic LDS for the 256^2 GEMM
  (void)hipFuncSetAttribute((const void*)k_gemm256,
                            hipFuncAttributeMaxDynamicSharedMemorySize, 65536);

  // fused prep (all casts + bias concat)
  k_castall<<<14340, 256, 0, stream>>>(x, Wq, Wk, Wv, Wg, Wo, bq, bk, bv, bg,
                                       xb, Wcat, Wob, bcat);

  // fused QKVG projection (256^2, A-staged / B-direct)
  k_gemm256<<<512, 512, 65536, stream>>>(xb, Wcat, Y, bcat);

  // t-contiguous K (decay-weighted) and V
  k_transpose<<<1024, 256, 0, stream>>>(Y, Ktd, Vt);

  // retention
  k_chunksum<<<512, 256, 0, stream>>>(Ktd, Vt, MS);
  k_scan<<<512, 256, 0, stream>>>(MS, Scb, stateOut);
  k_ret<<<512, 256, 0, stream>>>(Y, Vt, Scb, RG);

  // output projection
  k_gemm<1><<<(M_/128)*(E_/128), 256, 0, stream>>>(RG, Wob, (void*)outp, bo, M_, E_, E_, E_/128);
}

// Round 6
// 346.163 us; speedup vs baseline: 1.0404x; 1.0404x over previous
//
#include <hip/hip_runtime.h>
#include <hip/hip_bf16.h>

typedef __attribute__((ext_vector_type(8))) short short8;
typedef __attribute__((ext_vector_type(4))) short short4v;
typedef __attribute__((ext_vector_type(4))) float floatx4;

#define DI __device__ __forceinline__

// Problem constants
constexpr int B_ = 2, N_ = 2048, H_ = 16, DK_ = 128, DV_ = 128, E_ = 2048;
constexpr int M_ = B_ * N_;          // 4096 token rows
constexpr int NCAT_ = 4 * E_;        // 8192 = q|k|v|g concat
constexpr int CH_ = 128;             // chunk length
constexpr int NC_ = N_ / CH_;        // 16 chunks
constexpr float KSCALE = 0.08838834764831845f; // 1/sqrt(128)

// Workspace layout (bytes)
constexpr long OFF_XB   = 0;                    // 16MB  bf16 x      (reused as RG after GEMM1)
constexpr long OFF_WCAT = 16777216;             // 32MB  bf16 Wq|Wk|Wv|Wg  (reused as MS f32 after GEMM1)
constexpr long OFF_WOB  = 50331648;             // 8MB   bf16 Wo
constexpr long OFF_BCAT = 58720256;             // 32KB  f32 concat bias
constexpr long OFF_Y    = 58753024;             // 64MB  bf16 [4096][8192] q|k|v|silu(g)
constexpr long OFF_KT   = 125861888;            // 16MB  bf16 Ktd [b][h][dk][t]  (k * dec^-(t%128))
constexpr long OFF_VT   = 142639104;            // 16MB  bf16 Vt  [b][h][dv][t]
constexpr long OFF_SCB  = 159416320;            // 16MB  bf16 per-chunk start states [bh][c][dv][dk]

DI unsigned short f2bf(float f){
  unsigned u = __float_as_uint(f);
  u += 0x7fffu + ((u >> 16) & 1u);
  return (unsigned short)(u >> 16);
}
DI float bf2f(unsigned short s){ return __uint_as_float(((unsigned)s) << 16); }

DI void gload_lds16(const void* g, void* l){
  __builtin_amdgcn_global_load_lds(
      (const __attribute__((address_space(1))) unsigned int*)g,
      (__attribute__((address_space(3))) unsigned int*)l, 16, 0, 0);
}

// ---------------- fused prep: all f32->bf16 casts + bias concat ----------------
__global__ void k_castall(const float* __restrict__ x,
                          const float* __restrict__ Wq, const float* __restrict__ Wk,
                          const float* __restrict__ Wv, const float* __restrict__ Wg,
                          const float* __restrict__ Wo,
                          const float* __restrict__ bq, const float* __restrict__ bk,
                          const float* __restrict__ bv, const float* __restrict__ bg,
                          unsigned short* __restrict__ xb, unsigned short* __restrict__ Wcat,
                          unsigned short* __restrict__ Wob, float* __restrict__ bcat){
  int bid = blockIdx.x;
  if(bid >= 14336){
    int i = (bid - 14336) * 2048 + threadIdx.x * 8;
    #pragma unroll
    for(int u=0;u<8;++u){
      int j = i + u;
      float v;
      if(j < 2048)      v = bq[j];
      else if(j < 4096) v = bk[j - 2048];
      else if(j < 6144) v = bv[j - 4096];
      else              v = bg[j - 6144];
      bcat[j] = v;
    }
    return;
  }
  const float* s; unsigned short* d; long off;
  if(bid < 4096){ s = x; d = xb; off = (long)bid*2048; }
  else if(bid < 6144){ s = Wq; d = Wcat;            off = (long)(bid-4096)*2048; }
  else if(bid < 8192){ s = Wk; d = Wcat + 4194304L; off = (long)(bid-6144)*2048; }
  else if(bid < 10240){ s = Wv; d = Wcat + 8388608L; off = (long)(bid-8192)*2048; }
  else if(bid < 12288){ s = Wg; d = Wcat + 12582912L; off = (long)(bid-10240)*2048; }
  else { s = Wo; d = Wob; off = (long)(bid-12288)*2048; }
  long i = off + (long)threadIdx.x * 8;
  float4 v0 = *(const float4*)(s + i);
  float4 v1 = *(const float4*)(s + i + 4);
  short8 o;
  o[0]=(short)f2bf(v0.x); o[1]=(short)f2bf(v0.y); o[2]=(short)f2bf(v0.z); o[3]=(short)f2bf(v0.w);
  o[4]=(short)f2bf(v1.x); o[5]=(short)f2bf(v1.y); o[6]=(short)f2bf(v1.z); o[7]=(short)f2bf(v1.w);
  *(short8*)(d + i) = o;
}

// ================= 256x256 GEMM: A staged in LDS, B register-double-buffered =================
// 512 threads = 8 waves (2M x 4N), wave tile 128x64, BK=64. A-tile (256x64=32KB,
// 4-way wave-shared) double-buffered in LDS with XOR chunk swizzle. B-frags
// (2-way shared) prefetched ONE FULL K-TILE AHEAD into registers (bA/bB, 64 VGPR):
// issued right after __syncthreads, consumed next tile (~2500cy later), drained by
// next tile's syncthreads -> zero exposed latency, no lgkm dep on the B operand.
// LDS read demand drops to A only (~1/3 less), MFMA becomes the dominant pipe.
__global__ __launch_bounds__(512, 2)
void k_gemm256(const unsigned short* __restrict__ A,
               const unsigned short* __restrict__ Bt,
               unsigned short* __restrict__ Y,
               const float* __restrict__ bias)
{
  extern __shared__ unsigned short lds[];   // 2 buf x 16384 shorts (A tiles)
  constexpr int K = 2048;
  constexpr int NKT = K / 64;               // 32

  const int tid = threadIdx.x;
  const int wave = tid >> 6, lane = tid & 63;
  const int wr = wave >> 2, wc = wave & 3;
  const int l15 = lane & 15;

  // XCD-bijective 8x8 supertile swizzle
  int bid = blockIdx.x;
  int g = bid & 7, w = bid >> 3;
  int bm = (g & 1) * 8 + (w & 7);           // 0..15
  int bn = (g >> 1) * 8 + (w >> 3);         // 0..31

  const unsigned short* Ab = A  + (long)bm * 256 * K;

  // A staging geometry: 32 gloads of 1KB per tile; wave handles i = wave*4+s
  const int sr = (lane >> 3);                       // row-within-gload 0..7
  const int sc = ((lane & 7) ^ sr) * 8;             // pre-swizzled source col (elems)
  // A read geometry: row = wr*128+ai*16+l15; stored chunk pos = c ^ (row&7)
  int rbA[8];
  #pragma unroll
  for(int ai=0;ai<8;++ai) rbA[ai] = (wr*128 + ai*16 + l15) << 7;
  const int colx[2] = { ((0 + (lane>>4)) ^ (lane&7)) << 4,
                        ((4 + (lane>>4)) ^ (lane&7)) << 4 };

  // B direct-load base: frag (kk,bj): row = bn*256+wc*64+bj*16+l15,
  // col = kt*64 + kk*32 + (lane>>4)*8
  const unsigned short* Bp = Bt + (long)(bn*256 + wc*64 + l15) * K + ((lane >> 4) << 3);

  floatx4 acc[8][4] = {};
  const char* ldsc = (const char*)lds;
  short8 bA[2][4], bB[2][4];    // two named B tile-buffers (static indexing only)

#define STG_A(buf, kt) do{                                                            \
    _Pragma("unroll")                                                                 \
    for(int s=0;s<4;++s){                                                             \
      const int _i = wave*4 + s;                                                      \
      gload_lds16(Ab + (long)(_i*8 + sr)*K + (long)(kt)*64 + sc,                      \
                  &lds[(buf)*16384 + _i*512 + lane*8]);                               \
    }                                                                                 \
  }while(0)

#define LDB(dst, kt) do{                                                              \
    const unsigned short* _Bk = Bp + (long)(kt) * 64;                                 \
    _Pragma("unroll")                                                                 \
    for(int bj=0;bj<4;++bj){                                                          \
      dst[0][bj] = *(const short8*)(_Bk + (long)bj*16*K);                             \
      dst[1][bj] = *(const short8*)(_Bk + (long)bj*16*K + 32);                        \
    }                                                                                 \
  }while(0)

#define COMPUTE(buf, bregs) do{                                                       \
    const char* _cA = ldsc + (buf)*32768;                                             \
    _Pragma("unroll")                                                                 \
    for(int kk=0;kk<2;++kk){                                                          \
      short8 a8[8];                                                                   \
      _Pragma("unroll")                                                               \
      for(int ai=0;ai<8;++ai) a8[ai] = *(const short8*)(_cA + rbA[ai] + colx[kk]);    \
      _Pragma("unroll")                                                               \
      for(int ai=0;ai<8;++ai)                                                         \
        _Pragma("unroll")                                                             \
        for(int bj=0;bj<4;++bj)                                                       \
          acc[ai][bj] = __builtin_amdgcn_mfma_f32_16x16x32_bf16(                      \
              a8[ai], bregs[kk][bj], acc[ai][bj], 0,0,0);                             \
    }                                                                                 \
  }while(0)

  // prologue: A tile0 -> LDS buf0, B tile0 -> bA
  STG_A(0, 0);
  LDB(bA, 0);

  #pragma unroll 1
  for(int u=0; u<NKT; u+=2){
    __syncthreads();                 // A(buf0)+bA loads (issued a tile ago) done
    STG_A(1, u+1);                   // stage A tile u+1 -> buf1
    LDB(bB, u+1);                    // prefetch B tile u+1 -> regs
    COMPUTE(0, bA);                  // consume tile u

    __syncthreads();
    STG_A(0, (u+2) & (NKT-1));       // stage A tile u+2 -> buf0 (wraps harmlessly)
    LDB(bA, (u+2) & (NKT-1));        // prefetch B tile u+2
    COMPUTE(1, bB);                  // consume tile u+1
  }
#undef STG_A
#undef LDB
#undef COMPUTE

  // epilogue: bias + section transforms, bf16 store
  #pragma unroll
  for(int ai=0;ai<8;++ai){
    const int rowi = bm*256 + wr*128 + ai*16 + ((lane>>4)<<2);
    #pragma unroll
    for(int bj=0;bj<4;++bj){
      const int col = bn*256 + wc*64 + bj*16 + l15;
      const float bs = bias[col];
      const int sec = col >> 11;
      #pragma unroll
      for(int r=0;r<4;++r){
        float v = acc[ai][bj][r] + bs;
        if(sec == 1) v *= KSCALE;
        else if(sec == 3) v = v / (1.f + __expf(-v));   // silu
        Y[(long)(rowi + r) * NCAT_ + col] = f2bf(v);
      }
    }
  }
}

// ---------------- 128^2 GEMM, flat-pipelined double-buffer (output projection) ----------------
template<int EPI>
__global__ __launch_bounds__(256)
void k_gemm(const unsigned short* __restrict__ A,
            const unsigned short* __restrict__ Bt,
            void* __restrict__ outp,
            const float* __restrict__ bias,
            int M, int Ncols, int K, int NB)
{
  __shared__ unsigned short lA[2*128*64];
  __shared__ unsigned short lB[2*128*64];
  const int bid = blockIdx.x;
  const int bm = bid / NB, bn = bid % NB;
  const int tid = threadIdx.x;
  const int wave = tid >> 6, lane = tid & 63;
  const int wr = wave >> 1, wc = wave & 1;

  floatx4 acc[4][4] = {};

  int srow[4], scol[4];
  #pragma unroll
  for(int is=0; is<4; ++is){
    int o = is*4096 + wave*1024 + lane*16;     // byte offset in 16KB tile
    int row = o >> 7;
    int logcb = (o & 127) ^ ((row & 7) << 4);  // inverse-swizzled source column
    srow[is] = row; scol[is] = logcb >> 1;
  }
  const unsigned short* Abase = A + (long)bm * 128 * K;
  const unsigned short* Bbase = Bt + (long)bn * 128 * K;

#define STG128(kt, buf) do{                                                          \
    const int _k0 = (kt) << 6;                                                       \
    _Pragma("unroll")                                                                \
    for(int is=0; is<4; ++is){                                                       \
      gload_lds16(Abase + (long)srow[is]*K + _k0 + scol[is], &lA[(buf)*8192 + ((is*4096 + wave*1024) >> 1)]); \
      gload_lds16(Bbase + (long)srow[is]*K + _k0 + scol[is], &lB[(buf)*8192 + ((is*4096 + wave*1024) >> 1)]); \
    }                                                                                \
  }while(0)

  const int nkt = K >> 6;
  STG128(0, 0);
  for(int kt=0; kt<nkt; ++kt){
    const int cur = kt & 1, nxt = cur ^ 1;
    const int ktn = (kt + 1 == nkt) ? 0 : kt + 1;
    __syncthreads();
    STG128(ktn, nxt);
    const char* cA = (const char*)lA + cur*16384;
    const char* cB = (const char*)lB + cur*16384;
    #pragma unroll
    for(int kk=0; kk<2; ++kk){
      const int cb = (kk<<6) + ((lane>>4)<<4);
      short8 af[4], bfr[4];
      #pragma unroll
      for(int i=0;i<4;++i){
        int row = (wr<<6) + (i<<4) + (lane&15);
        af[i] = *(const short8*)(cA + (row<<7) + (cb ^ ((row&7)<<4)));
      }
      #pragma unroll
      for(int j=0;j<4;++j){
        int row = (wc<<6) + (j<<4) + (lane&15);
        bfr[j] = *(const short8*)(cB + (row<<7) + (cb ^ ((row&7)<<4)));
      }
      #pragma unroll
      for(int i=0;i<4;++i)
        #pragma unroll
        for(int j=0;j<4;++j)
          acc[i][j] = __builtin_amdgcn_mfma_f32_16x16x32_bf16(af[i], bfr[j], acc[i][j], 0,0,0);
    }
  }
#undef STG128

  #pragma unroll
  for(int i=0;i<4;++i){
    #pragma unroll
    for(int j=0;j<4;++j){
      #pragma unroll
      for(int r=0;r<4;++r){
        int row = bm*128 + (wr<<6) + (i<<4) + ((lane>>4)<<2) + r;
        int col = bn*128 + (wc<<6) + (j<<4) + (lane&15);
        float v = acc[i][j][r] + bias[col];
        if(EPI == 0){
          int sec = col >> 11;
          if(sec == 1) v *= KSCALE;
          else if(sec == 3) v = v / (1.f + __expf(-v));   // silu
          ((unsigned short*)outp)[(long)row * Ncols + col] = f2bf(v);
        } else {
          ((float*)outp)[(long)row * Ncols + col] = v;
        }
      }
    }
  }
}

// ---------------- transpose K,V to t-contiguous; bake dec^-(t%128) into K ----------------
__global__ __launch_bounds__(256)
void k_transpose(const unsigned short* __restrict__ Y,
                 unsigned short* __restrict__ Kt, unsigned short* __restrict__ Vt){
  __shared__ unsigned short lt[128][136];
  int bid = blockIdx.x;
  int op = bid >> 9;            // 0: K, 1: V
  int r  = bid & 511;
  int bh = r >> 4, c = r & 15, b = bh >> 4, h = bh & 15;
  int tid = threadIdx.x;
  float dec = 1.f - exp2f(-5.f - (float)h);
  float l2d = log2f(dec);
  int sec = op ? 4096 : 2048;
  unsigned short* Dst = op ? Vt : Kt;

  #pragma unroll
  for(int p=0;p<8;++p){
    int t = p*16 + (tid>>4);
    long src = ((long)(b*N_ + c*CH_ + t)) * NCAT_ + sec + h*128 + (tid&15)*8;
    short8 v = *(const short8*)(Y + src);
    if(op == 0){
      float f = exp2f(-(float)t * l2d);   // dec^{-t}
      #pragma unroll
      for(int u=0;u<8;++u) v[u] = (short)f2bf(bf2f((unsigned short)v[u]) * f);
    }
    *(short8*)&lt[t][(tid&15)*8] = v;
  }
  __syncthreads();
  #pragma unroll
  for(int p=0;p<8;++p){
    int dk = p*16 + (tid>>4);
    int tc = (tid&15)*8;
    short8 o;
    #pragma unroll
    for(int u=0;u<8;++u) o[u] = (short)lt[tc+u][dk];
    *(short8*)(Dst + ((long)(bh*128 + dk)) * N_ + c*CH_ + tc) = o;
  }
}

// ---------------- per-chunk summary Mt_c[dv][dk] = dec^{C-1} * sum_t Vt[dv][t]*Ktd[dk][t] ----------------
__global__ __launch_bounds__(256)
void k_chunksum(const unsigned short* __restrict__ Ktd, const unsigned short* __restrict__ Vt,
                float* __restrict__ MS){
  int bid = blockIdx.x;            // 512: bh*16 + c
  int bh = bid >> 4, c = bid & 15, h = bh & 15;
  int tid = threadIdx.x, wave = tid >> 6, lane = tid & 63;
  int wr = wave >> 1, wc = wave & 1;
  floatx4 acc[4][4] = {};
  const unsigned short* Vb = Vt  + (long)bh*128*N_ + c*CH_;
  const unsigned short* Kb = Ktd + (long)bh*128*N_ + c*CH_;

  #pragma unroll
  for(int kk=0;kk<4;++kk){
    int tl = kk*32 + ((lane>>4)<<3);
    short8 af[4], bfr[4];
    #pragma unroll
    for(int i=0;i<4;++i){ int dv = (wr<<6)+(i<<4)+(lane&15); af[i]  = *(const short8*)(Vb + (long)dv*N_ + tl); }
    #pragma unroll
    for(int j=0;j<4;++j){ int dk = (wc<<6)+(j<<4)+(lane&15); bfr[j] = *(const short8*)(Kb + (long)dk*N_ + tl); }
    #pragma unroll
    for(int i=0;i<4;++i)
      #pragma unroll
      for(int j=0;j<4;++j)
        acc[i][j] = __builtin_amdgcn_mfma_f32_16x16x32_bf16(af[i], bfr[j], acc[i][j], 0,0,0);
  }
  float dec = 1.f - exp2f(-5.f - (float)h);
  float scale = exp2f(127.f * log2f(dec));    // dec^{C-1}
  float* Mo = MS + ((long)bh*NC_ + c) * 16384;
  #pragma unroll
  for(int i=0;i<4;++i)
    #pragma unroll
    for(int j=0;j<4;++j)
      #pragma unroll
      for(int r=0;r<4;++r){
        int dv = (wr<<6)+(i<<4)+((lane>>4)<<2)+r;
        int dk = (wc<<6)+(j<<4)+(lane&15);
        Mo[dv*128 + dk] = acc[i][j][r] * scale;
      }
}

// ---------------- parallel scan over chunks (elementwise over state entries) ----------------
__global__ __launch_bounds__(256)
void k_scan(const float* __restrict__ MS, unsigned short* __restrict__ Scb,
            float* __restrict__ stateOut){
  int bid = blockIdx.x;
  int bh = bid >> 4, p = bid & 15;
  int tid = threadIdx.x, h = bh & 15;
  float dec = 1.f - exp2f(-5.f - (float)h);
  float decC = exp2f(128.f * log2f(dec));     // dec^C
  int e0 = p*1024 + tid*4;
  floatx4 S = {0.f, 0.f, 0.f, 0.f};
  const float* base = MS + (long)bh * NC_ * 16384 + e0;
  unsigned short* sb = Scb + (long)bh * NC_ * 16384 + e0;
  for(int c=0;c<NC_;++c){
    floatx4 m = *(const floatx4*)(base + (long)c*16384);
    short4v q;
    #pragma unroll
    for(int u=0;u<4;++u) q[u] = (short)f2bf(S[u]);
    *(short4v*)(sb + (long)c*16384) = q;
    S = decC * S + m;
  }
  // final state: element e = dv*128+dk (transposed layout) -> out [b][h][dk][dv]
  int dv = e0 >> 7, dk = e0 & 127;
  float* so = stateOut + (long)bh*16384 + dv;
  #pragma unroll
  for(int u=0;u<4;++u) so[(long)(dk+u)*128] = S[u];
}

// ---------------- retention output: masked decayed QK^T @ V + cross, group-norm, gate ----------------
__global__ __launch_bounds__(256)
void k_ret(const unsigned short* __restrict__ Y, const unsigned short* __restrict__ Vt,
           const unsigned short* __restrict__ Scb, unsigned short* __restrict__ RG){
  __shared__ unsigned short sQ[128*128];   // Qd = q * dec^t   (swizzled)
  __shared__ unsigned short sK[128*128];   // Kd = k * dec^-s ; reused for P
  int bid = blockIdx.x;
  int bh = bid >> 4, c = bid & 15, b = bh >> 4, h = bh & 15;
  int tid = threadIdx.x, w = tid >> 6, lane = tid & 63;
  float dec = 1.f - exp2f(-5.f - (float)h);
  float l2d = log2f(dec);

  #pragma unroll
  for(int p=0;p<8;++p){
    int t = p*16 + (tid>>4);
    long row = (long)(b*N_ + c*CH_ + t) * NCAT_ + h*128 + (tid&15)*8;
    short8 qv = *(const short8*)(Y + row);          // q section
    short8 kv = *(const short8*)(Y + row + 2048);   // k section
    float fq = exp2f((float)t * l2d);
    float fk = exp2f(-(float)t * l2d);
    short8 qs, ks;
    #pragma unroll
    for(int u=0;u<8;++u){
      qs[u] = (short)f2bf(bf2f((unsigned short)qv[u]) * fq);
      ks[u] = (short)f2bf(bf2f((unsigned short)kv[u]) * fk);
    }
    int ad = t*256 + (((tid&15)*16) ^ ((t&7)<<4));
    *(short8*)((char*)sQ + ad) = qs;
    *(short8*)((char*)sK + ad) = ks;
  }
  __syncthreads();

  floatx4 acc[2][8] = {};
  // QK^T (already includes dec^{t-s})
  #pragma unroll
  for(int kk=0;kk<4;++kk){
    int cb = (kk<<6) + ((lane>>4)<<4);
    short8 af[2], bfr[8];
    #pragma unroll
    for(int i=0;i<2;++i){ int t = w*32 + (i<<4) + (lane&15); af[i] = *(const short8*)((const char*)sQ + t*256 + (cb ^ ((t&7)<<4))); }
    #pragma unroll
    for(int j=0;j<8;++j){ int s = (j<<4) + (lane&15); bfr[j] = *(const short8*)((const char*)sK + s*256 + (cb ^ ((s&7)<<4))); }
    #pragma unroll
    for(int i=0;i<2;++i)
      #pragma unroll
      for(int j=0;j<8;++j)
        acc[i][j] = __builtin_amdgcn_mfma_f32_16x16x32_bf16(af[i], bfr[j], acc[i][j], 0,0,0);
  }
  __syncthreads();   // all waves done reading sK

  // causal mask, write P (bf16) into sK
  #pragma unroll
  for(int i=0;i<2;++i)
    #pragma unroll
    for(int j=0;j<8;++j)
      #pragma unroll
      for(int r=0;r<4;++r){
        int t = w*32 + (i<<4) + ((lane>>4)<<2) + r;
        int s = (j<<4) + (lane&15);
        float v = (s <= t) ? acc[i][j][r] : 0.f;
        *(unsigned short*)((char*)sK + t*256 + ((s*2) ^ ((t&7)<<4))) = f2bf(v);
      }
  __syncthreads();

  #pragma unroll
  for(int i=0;i<2;++i)
    #pragma unroll
    for(int j=0;j<8;++j)
      #pragma unroll
      for(int u=0;u<4;++u) acc[i][j][u] = 0.f;

  // ret = P @ V
  const unsigned short* Vb = Vt + (long)bh*128*N_ + c*CH_;
  #pragma unroll
  for(int kk=0;kk<4;++kk){
    int cb = (kk<<6) + ((lane>>4)<<4);
    int sg = kk*32 + ((lane>>4)<<3);
    short8 af[2], bfr[8];
    #pragma unroll
    for(int i=0;i<2;++i){ int t = w*32 + (i<<4) + (lane&15); af[i] = *(const short8*)((const char*)sK + t*256 + (cb ^ ((t&7)<<4))); }
    #pragma unroll
    for(int j=0;j<8;++j){ int dv = (j<<4) + (lane&15); bfr[j] = *(const short8*)(Vb + (long)dv*N_ + sg); }
    #pragma unroll
    for(int i=0;i<2;++i)
      #pragma unroll
      for(int j=0;j<8;++j)
        acc[i][j] = __builtin_amdgcn_mfma_f32_16x16x32_bf16(af[i], bfr[j], acc[i][j], 0,0,0);
  }
  // + dec^{t+1} * q @ S_c   (A = Qd*dec, B = Scb[dv][dk])
  const unsigned short* Sb = Scb + ((long)bh*NC_ + c) * 16384;
  #pragma unroll
  for(int kk=0;kk<4;++kk){
    int cb = (kk<<6) + ((lane>>4)<<4);
    int kg = kk*32 + ((lane>>4)<<3);
    short8 af[2], bfr[8];
    #pragma unroll
    for(int i=0;i<2;++i){
      int t = w*32 + (i<<4) + (lane&15);
      short8 qv = *(const short8*)((const char*)sQ + t*256 + (cb ^ ((t&7)<<4)));
      #pragma unroll
      for(int u=0;u<8;++u) af[i][u] = (short)f2bf(bf2f((unsigned short)qv[u]) * dec);
    }
    #pragma unroll
    for(int j=0;j<8;++j){ int dv = (j<<4) + (lane&15); bfr[j] = *(const short8*)(Sb + (long)dv*128 + kg); }
    #pragma unroll
    for(int i=0;i<2;++i)
      #pragma unroll
      for(int j=0;j<8;++j)
        acc[i][j] = __builtin_amdgcn_mfma_f32_16x16x32_bf16(af[i], bfr[j], acc[i][j], 0,0,0);
  }

  // group-norm over DV per row, gate, write bf16
  #pragma unroll
  for(int i=0;i<2;++i){
    #pragma unroll
    for(int r=0;r<4;++r){
      float s1 = 0.f, s2 = 0.f;
      #pragma unroll
      for(int j=0;j<8;++j){ float v = acc[i][j][r]; s1 += v; s2 += v*v; }
      #pragma unroll
      for(int off=1; off<16; off<<=1){ s1 += __shfl_xor(s1, off); s2 += __shfl_xor(s2, off); }
      float mu  = s1 * (1.f/128.f);
      float var = s2 * (1.f/128.f) - mu*mu;
      float inv = rsqrtf(var + 1e-6f);
      int t = w*32 + (i<<4) + ((lane>>4)<<2) + r;
      long mrow = (long)(b*N_ + c*CH_ + t);
      #pragma unroll
      for(int j=0;j<8;++j){
        int dv = (j<<4) + (lane&15);
        float v = (acc[i][j][r] - mu) * inv;
        float g = bf2f(Y[mrow*NCAT_ + 6144 + h*128 + dv]);
        RG[mrow*E_ + h*128 + dv] = f2bf(v * g);
      }
    }
  }
}

// ---------------- launch ----------------
extern "C" void kernel_launch(void* const* d_in, const int* in_sizes, int n_in,
                              void* d_out, int out_size, void* d_ws, size_t ws_size,
                              hipStream_t stream) {
  const float* x  = (const float*)d_in[0];
  const float* Wq = (const float*)d_in[1];
  const float* bq = (const float*)d_in[2];
  const float* Wk = (const float*)d_in[3];
  const float* bk = (const float*)d_in[4];
  const float* Wv = (const float*)d_in[5];
  const float* bv = (const float*)d_in[6];
  const float* Wg = (const float*)d_in[7];
  const float* bg = (const float*)d_in[8];
  const float* Wo = (const float*)d_in[9];
  const float* bo = (const float*)d_in[10];

  char* ws = (char*)d_ws;
  unsigned short* xb   = (unsigned short*)(ws + OFF_XB);
  unsigned short* Wcat = (unsigned short*)(ws + OFF_WCAT);
  unsigned short* Wob  = (unsigned short*)(ws + OFF_WOB);
  float*          bcat = (float*)(ws + OFF_BCAT);
  unsigned short* Y    = (unsigned short*)(ws + OFF_Y);
  unsigned short* Ktd  = (unsigned short*)(ws + OFF_KT);
  unsigned short* Vt   = (unsigned short*)(ws + OFF_VT);
  unsigned short* Scb  = (unsigned short*)(ws + OFF_SCB);
  float*          MS   = (float*)(ws + OFF_WCAT);   // reuse after GEMM1
  unsigned short* RG   = (unsigned short*)(ws + OFF_XB); // reuse after GEMM1

  float* outp     = (float*)d_out;
  float* stateOut = outp + (long)M_ * E_;   // 8,388,608

  // allow 64KB dynamic LDS for the 256^2 GEMM
  (void)hipFuncSetAttribute((const void*)k_gemm256,
                            hipFuncAttributeMaxDynamicSharedMemorySize, 65536);

  // fused prep (all casts + bias concat)
  k_castall<<<14340, 256, 0, stream>>>(x, Wq, Wk, Wv, Wg, Wo, bq, bk, bv, bg,
                                       xb, Wcat, Wob, bcat);

  // fused QKVG projection (256^2, A-LDS / B-reg-dbuf)
  k_gemm256<<<512, 512, 65536, stream>>>(xb, Wcat, Y, bcat);

  // t-contiguous K (decay-weighted) and V
  k_transpose<<<1024, 256, 0, stream>>>(Y, Ktd, Vt);

  // retention
  k_chunksum<<<512, 256, 0, stream>>>(Ktd, Vt, MS);
  k_scan<<<512, 256, 0, stream>>>(MS, Scb, stateOut);
  k_ret<<<512, 256, 0, stream>>>(Y, Vt, Scb, RG);

  // output projection
  k_gemm<1><<<(M_/128)*(E_/128), 256, 0, stream>>>(RG, Wob, (void*)outp, bo, M_, E_, E_, E_/128);
}

// Round 7
// 282.895 us; speedup vs baseline: 1.2731x; 1.2236x over previous
//
#include <hip/hip_runtime.h>
#include <hip/hip_bf16.h>

typedef __attribute__((ext_vector_type(8))) short short8;
typedef __attribute__((ext_vector_type(4))) short short4v;
typedef __attribute__((ext_vector_type(4))) float floatx4;

#define DI __device__ __forceinline__

// Problem constants
constexpr int B_ = 2, N_ = 2048, H_ = 16, DK_ = 128, DV_ = 128, E_ = 2048;
constexpr int M_ = B_ * N_;          // 4096 token rows
constexpr int NCAT_ = 4 * E_;        // 8192 = q|k|v|g concat
constexpr int CH_ = 128;             // chunk length
constexpr int NC_ = N_ / CH_;        // 16 chunks
constexpr float KSCALE = 0.08838834764831845f; // 1/sqrt(128)

// Workspace layout (bytes)
constexpr long OFF_XB   = 0;                    // 16MB  bf16 x      (reused as RG after GEMM1)
constexpr long OFF_WCAT = 16777216;             // 32MB  bf16 Wq|Wk|Wv|Wg  (reused as MS f32 after GEMM1)
constexpr long OFF_WOB  = 50331648;             // 8MB   bf16 Wo
constexpr long OFF_BCAT = 58720256;             // 32KB  f32 concat bias
constexpr long OFF_Y    = 58753024;             // 64MB  bf16 [4096][8192] q|k|v|silu(g)
constexpr long OFF_KT   = 125861888;            // 16MB  bf16 Ktd [b][h][dk][t]  (k * dec^-(t%128))
constexpr long OFF_VT   = 142639104;            // 16MB  bf16 Vt  [b][h][dv][t]
constexpr long OFF_SCB  = 159416320;            // 16MB  bf16 per-chunk start states [bh][c][dv][dk]

DI unsigned short f2bf(float f){
  unsigned u = __float_as_uint(f);
  u += 0x7fffu + ((u >> 16) & 1u);
  return (unsigned short)(u >> 16);
}
DI float bf2f(unsigned short s){ return __uint_as_float(((unsigned)s) << 16); }

DI void gload_lds16(const void* g, void* l){
  __builtin_amdgcn_global_load_lds(
      (const __attribute__((address_space(1))) unsigned int*)g,
      (__attribute__((address_space(3))) unsigned int*)l, 16, 0, 0);
}

// ---------------- fused prep: all f32->bf16 casts + bias concat ----------------
__global__ void k_castall(const float* __restrict__ x,
                          const float* __restrict__ Wq, const float* __restrict__ Wk,
                          const float* __restrict__ Wv, const float* __restrict__ Wg,
                          const float* __restrict__ Wo,
                          const float* __restrict__ bq, const float* __restrict__ bk,
                          const float* __restrict__ bv, const float* __restrict__ bg,
                          unsigned short* __restrict__ xb, unsigned short* __restrict__ Wcat,
                          unsigned short* __restrict__ Wob, float* __restrict__ bcat){
  int bid = blockIdx.x;
  if(bid >= 14336){
    int i = (bid - 14336) * 2048 + threadIdx.x * 8;
    #pragma unroll
    for(int u=0;u<8;++u){
      int j = i + u;
      float v;
      if(j < 2048)      v = bq[j];
      else if(j < 4096) v = bk[j - 2048];
      else if(j < 6144) v = bv[j - 4096];
      else              v = bg[j - 6144];
      bcat[j] = v;
    }
    return;
  }
  const float* s; unsigned short* d; long off;
  if(bid < 4096){ s = x; d = xb; off = (long)bid*2048; }
  else if(bid < 6144){ s = Wq; d = Wcat;            off = (long)(bid-4096)*2048; }
  else if(bid < 8192){ s = Wk; d = Wcat + 4194304L; off = (long)(bid-6144)*2048; }
  else if(bid < 10240){ s = Wv; d = Wcat + 8388608L; off = (long)(bid-8192)*2048; }
  else if(bid < 12288){ s = Wg; d = Wcat + 12582912L; off = (long)(bid-10240)*2048; }
  else { s = Wo; d = Wob; off = (long)(bid-12288)*2048; }
  long i = off + (long)threadIdx.x * 8;
  float4 v0 = *(const float4*)(s + i);
  float4 v1 = *(const float4*)(s + i + 4);
  short8 o;
  o[0]=(short)f2bf(v0.x); o[1]=(short)f2bf(v0.y); o[2]=(short)f2bf(v0.z); o[3]=(short)f2bf(v0.w);
  o[4]=(short)f2bf(v1.x); o[5]=(short)f2bf(v1.y); o[6]=(short)f2bf(v1.z); o[7]=(short)f2bf(v1.w);
  *(short8*)(d + i) = o;
}

// ================= 256x256 GEMM, quadrant-phase with read-ahead slots =================
// 512 threads = 8 waves (2M x 4N), wave tile 128x64, BK=64. A+B staged via
// gload_lds into 128KB double-buffered LDS (XOR chunk swizzle, R4 structure).
// Schedule: 4 phases per K-tile, each = one wave-quadrant (64x32) x K=64 (16 MFMA).
// Every phase's ds_reads are issued >=1 full MFMA-cluster BEFORE their consuming
// phase (persistent slots Aa/Ab/Ba/Bb), so LDS service hides under MFMA.
// Tile-boundary vmcnt(0)+barrier at P2/P3 seam; P3 reads the NEXT buffer and
// restages tile u+2 (staging gets a full tile of flight).
__global__ __launch_bounds__(512, 2)
void k_gemm256(const unsigned short* __restrict__ A,
               const unsigned short* __restrict__ Bt,
               unsigned short* __restrict__ Y,
               const float* __restrict__ bias)
{
  extern __shared__ unsigned short lds[];   // A: [0,64KB) 2 bufs; B: [64KB,128KB) 2 bufs
  constexpr int K = 2048;
  constexpr int NKT = K / 64;               // 32

  const int tid = threadIdx.x;
  const int wave = tid >> 6, lane = tid & 63;
  const int wr = wave >> 2, wc = wave & 3;
  const int l15 = lane & 15;

  // XCD-bijective 8x8 supertile swizzle
  int bid = blockIdx.x;
  int g = bid & 7, w = bid >> 3;
  int bm = (g & 1) * 8 + (w & 7);           // 0..15
  int bn = (g >> 1) * 8 + (w >> 3);         // 0..31

  const unsigned short* Ag = A  + (long)bm * 256 * K;
  const unsigned short* Bg = Bt + (long)bn * 256 * K;

  // staging geometry (R4): gload i (=wave*4+s) covers rows i*8+sr, pre-swizzled col sc
  const int sr = (lane >> 3);
  const int sc = ((lane & 7) ^ sr) * 8;
  // read geometry
  const int colx[2] = { ((0 + (lane>>4)) ^ (lane&7)) << 4,
                        ((4 + (lane>>4)) ^ (lane&7)) << 4 };

  floatx4 acc[8][4] = {};     // [mh*4+ai][nh*2+bj]
  const char* ldsc = (const char*)lds;

  short8 Aa[8], Ab[8], Ba[4], Bb[4];   // persistent operand slots (96 VGPR)

#define STG(buf, kt) do{                                                              \
    _Pragma("unroll")                                                                 \
    for(int s=0;s<4;++s){                                                             \
      const int _i = wave*4 + s;                                                      \
      gload_lds16(Ag + (long)(_i*8 + sr)*K + (long)(kt)*64 + sc,                      \
                  &lds[(buf)*16384 + _i*512 + lane*8]);                               \
      gload_lds16(Bg + (long)(_i*8 + sr)*K + (long)(kt)*64 + sc,                      \
                  &lds[32768 + (buf)*16384 + _i*512 + lane*8]);                       \
    }                                                                                 \
  }while(0)

#define RD_A(dst, cbuf, mh) do{                                                       \
    const char* _b = ldsc + (cbuf)*32768;                                             \
    _Pragma("unroll")                                                                 \
    for(int ai=0;ai<4;++ai){                                                          \
      const int _rb = (wr*128 + (mh)*64 + ai*16 + l15) << 7;                          \
      dst[ai*2+0] = *(const short8*)(_b + _rb + colx[0]);                             \
      dst[ai*2+1] = *(const short8*)(_b + _rb + colx[1]);                             \
    }                                                                                 \
  }while(0)

#define RD_B(dst, cbuf, nh) do{                                                       \
    const char* _b = ldsc + 65536 + (cbuf)*32768;                                     \
    _Pragma("unroll")                                                                 \
    for(int bj=0;bj<2;++bj){                                                          \
      const int _rb = (wc*64 + (nh)*32 + bj*16 + l15) << 7;                           \
      dst[bj*2+0] = *(const short8*)(_b + _rb + colx[0]);                             \
      dst[bj*2+1] = *(const short8*)(_b + _rb + colx[1]);                             \
    }                                                                                 \
  }while(0)

#define MFQ(mh, nh, As, Bs) do{                                                       \
    __builtin_amdgcn_s_setprio(1);                                                    \
    _Pragma("unroll")                                                                 \
    for(int ai=0;ai<4;++ai)                                                           \
      _Pragma("unroll")                                                               \
      for(int bj=0;bj<2;++bj)                                                         \
        _Pragma("unroll")                                                             \
        for(int kk=0;kk<2;++kk)                                                       \
          acc[(mh)*4+ai][(nh)*2+bj] = __builtin_amdgcn_mfma_f32_16x16x32_bf16(        \
              As[ai*2+kk], Bs[bj*2+kk], acc[(mh)*4+ai][(nh)*2+bj], 0,0,0);            \
    __builtin_amdgcn_s_setprio(0);                                                    \
  }while(0)

#define SBAR  __builtin_amdgcn_s_barrier()
#define SCHED __builtin_amdgcn_sched_barrier(0)

  // prologue: stage tiles 0,1; wait tile0 (8 of 16 loads); preload Aa/Ba from buf0
  STG(0, 0);
  STG(1, 1);
  asm volatile("s_waitcnt vmcnt(8)" ::: "memory");
  SBAR;
  RD_A(Aa, 0, 0);
  RD_B(Ba, 0, 0);
  SCHED;

  #pragma unroll 1
  for(int u=0; u<NKT; ++u){
    const int cur = u & 1, nxt = cur ^ 1;

    // P0: issue reads for P1/P3 operands (A1,B1 of this tile); MFMA Q00
    RD_A(Ab, cur, 1);
    RD_B(Bb, cur, 1);
    SCHED;
    SBAR;
    MFQ(0, 0, Aa, Ba);         // uses Aa,Ba (loaded last tile's P3 / prologue)
    SBAR; SCHED;

    // P1: MFMA Q01 (Aa, Bb)
    MFQ(0, 1, Aa, Bb);
    SBAR; SCHED;

    // P2: MFMA Q10 (Ab, Ba)
    MFQ(1, 0, Ab, Ba);
    // tile boundary: all reads of buf cur are done (last issued at P0);
    // next buf's staging loads (issued last tile's P3 / prologue) must land.
    asm volatile("s_waitcnt vmcnt(0)" ::: "memory");
    SBAR; SCHED;

    // P3: restage cur buf for tile u+2; read next tile's Aa/Ba from nxt buf; MFMA Q11
    STG(cur, (u + 2) & (NKT - 1));
    RD_A(Aa, nxt, 0);
    RD_B(Ba, nxt, 0);
    SCHED;
    MFQ(1, 1, Ab, Bb);
    SCHED;
  }
#undef STG
#undef RD_A
#undef RD_B
#undef MFQ
#undef SBAR
#undef SCHED

  // epilogue: bias + section transforms, bf16 store
  #pragma unroll
  for(int mh=0;mh<2;++mh){
    #pragma unroll
    for(int ai=0;ai<4;++ai){
      const int rowi = bm*256 + wr*128 + mh*64 + ai*16 + ((lane>>4)<<2);
      #pragma unroll
      for(int nh=0;nh<2;++nh){
        #pragma unroll
        for(int bj=0;bj<2;++bj){
          const int col = bn*256 + wc*64 + nh*32 + bj*16 + l15;
          const float bs = bias[col];
          const int sec = col >> 11;
          #pragma unroll
          for(int r=0;r<4;++r){
            float v = acc[mh*4+ai][nh*2+bj][r] + bs;
            if(sec == 1) v *= KSCALE;
            else if(sec == 3) v = v / (1.f + __expf(-v));   // silu
            Y[(long)(rowi + r) * NCAT_ + col] = f2bf(v);
          }
        }
      }
    }
  }
}

// ---------------- 128^2 GEMM, flat-pipelined double-buffer (output projection) ----------------
template<int EPI>
__global__ __launch_bounds__(256)
void k_gemm(const unsigned short* __restrict__ A,
            const unsigned short* __restrict__ Bt,
            void* __restrict__ outp,
            const float* __restrict__ bias,
            int M, int Ncols, int K, int NB)
{
  __shared__ unsigned short lA[2*128*64];
  __shared__ unsigned short lB[2*128*64];
  const int bid = blockIdx.x;
  const int bm = bid / NB, bn = bid % NB;
  const int tid = threadIdx.x;
  const int wave = tid >> 6, lane = tid & 63;
  const int wr = wave >> 1, wc = wave & 1;

  floatx4 acc[4][4] = {};

  int srow[4], scol[4];
  #pragma unroll
  for(int is=0; is<4; ++is){
    int o = is*4096 + wave*1024 + lane*16;     // byte offset in 16KB tile
    int row = o >> 7;
    int logcb = (o & 127) ^ ((row & 7) << 4);  // inverse-swizzled source column
    srow[is] = row; scol[is] = logcb >> 1;
  }
  const unsigned short* Abase = A + (long)bm * 128 * K;
  const unsigned short* Bbase = Bt + (long)bn * 128 * K;

#define STG128(kt, buf) do{                                                          \
    const int _k0 = (kt) << 6;                                                       \
    _Pragma("unroll")                                                                \
    for(int is=0; is<4; ++is){                                                       \
      gload_lds16(Abase + (long)srow[is]*K + _k0 + scol[is], &lA[(buf)*8192 + ((is*4096 + wave*1024) >> 1)]); \
      gload_lds16(Bbase + (long)srow[is]*K + _k0 + scol[is], &lB[(buf)*8192 + ((is*4096 + wave*1024) >> 1)]); \
    }                                                                                \
  }while(0)

  const int nkt = K >> 6;
  STG128(0, 0);
  for(int kt=0; kt<nkt; ++kt){
    const int cur = kt & 1, nxt = cur ^ 1;
    const int ktn = (kt + 1 == nkt) ? 0 : kt + 1;
    __syncthreads();
    STG128(ktn, nxt);
    const char* cA = (const char*)lA + cur*16384;
    const char* cB = (const char*)lB + cur*16384;
    #pragma unroll
    for(int kk=0; kk<2; ++kk){
      const int cb = (kk<<6) + ((lane>>4)<<4);
      short8 af[4], bfr[4];
      #pragma unroll
      for(int i=0;i<4;++i){
        int row = (wr<<6) + (i<<4) + (lane&15);
        af[i] = *(const short8*)(cA + (row<<7) + (cb ^ ((row&7)<<4)));
      }
      #pragma unroll
      for(int j=0;j<4;++j){
        int row = (wc<<6) + (j<<4) + (lane&15);
        bfr[j] = *(const short8*)(cB + (row<<7) + (cb ^ ((row&7)<<4)));
      }
      #pragma unroll
      for(int i=0;i<4;++i)
        #pragma unroll
        for(int j=0;j<4;++j)
          acc[i][j] = __builtin_amdgcn_mfma_f32_16x16x32_bf16(af[i], bfr[j], acc[i][j], 0,0,0);
    }
  }
#undef STG128

  #pragma unroll
  for(int i=0;i<4;++i){
    #pragma unroll
    for(int j=0;j<4;++j){
      #pragma unroll
      for(int r=0;r<4;++r){
        int row = bm*128 + (wr<<6) + (i<<4) + ((lane>>4)<<2) + r;
        int col = bn*128 + (wc<<6) + (j<<4) + (lane&15);
        float v = acc[i][j][r] + bias[col];
        if(EPI == 0){
          int sec = col >> 11;
          if(sec == 1) v *= KSCALE;
          else if(sec == 3) v = v / (1.f + __expf(-v));   // silu
          ((unsigned short*)outp)[(long)row * Ncols + col] = f2bf(v);
        } else {
          ((float*)outp)[(long)row * Ncols + col] = v;
        }
      }
    }
  }
}

// ---------------- transpose K,V to t-contiguous; bake dec^-(t%128) into K ----------------
__global__ __launch_bounds__(256)
void k_transpose(const unsigned short* __restrict__ Y,
                 unsigned short* __restrict__ Kt, unsigned short* __restrict__ Vt){
  __shared__ unsigned short lt[128][136];
  int bid = blockIdx.x;
  int op = bid >> 9;            // 0: K, 1: V
  int r  = bid & 511;
  int bh = r >> 4, c = r & 15, b = bh >> 4, h = bh & 15;
  int tid = threadIdx.x;
  float dec = 1.f - exp2f(-5.f - (float)h);
  float l2d = log2f(dec);
  int sec = op ? 4096 : 2048;
  unsigned short* Dst = op ? Vt : Kt;

  #pragma unroll
  for(int p=0;p<8;++p){
    int t = p*16 + (tid>>4);
    long src = ((long)(b*N_ + c*CH_ + t)) * NCAT_ + sec + h*128 + (tid&15)*8;
    short8 v = *(const short8*)(Y + src);
    if(op == 0){
      float f = exp2f(-(float)t * l2d);   // dec^{-t}
      #pragma unroll
      for(int u=0;u<8;++u) v[u] = (short)f2bf(bf2f((unsigned short)v[u]) * f);
    }
    *(short8*)&lt[t][(tid&15)*8] = v;
  }
  __syncthreads();
  #pragma unroll
  for(int p=0;p<8;++p){
    int dk = p*16 + (tid>>4);
    int tc = (tid&15)*8;
    short8 o;
    #pragma unroll
    for(int u=0;u<8;++u) o[u] = (short)lt[tc+u][dk];
    *(short8*)(Dst + ((long)(bh*128 + dk)) * N_ + c*CH_ + tc) = o;
  }
}

// ---------------- per-chunk summary Mt_c[dv][dk] = dec^{C-1} * sum_t Vt[dv][t]*Ktd[dk][t] ----------------
__global__ __launch_bounds__(256)
void k_chunksum(const unsigned short* __restrict__ Ktd, const unsigned short* __restrict__ Vt,
                float* __restrict__ MS){
  int bid = blockIdx.x;            // 512: bh*16 + c
  int bh = bid >> 4, c = bid & 15, h = bh & 15;
  int tid = threadIdx.x, wave = tid >> 6, lane = tid & 63;
  int wr = wave >> 1, wc = wave & 1;
  floatx4 acc[4][4] = {};
  const unsigned short* Vb = Vt  + (long)bh*128*N_ + c*CH_;
  const unsigned short* Kb = Ktd + (long)bh*128*N_ + c*CH_;

  #pragma unroll
  for(int kk=0;kk<4;++kk){
    int tl = kk*32 + ((lane>>4)<<3);
    short8 af[4], bfr[4];
    #pragma unroll
    for(int i=0;i<4;++i){ int dv = (wr<<6)+(i<<4)+(lane&15); af[i]  = *(const short8*)(Vb + (long)dv*N_ + tl); }
    #pragma unroll
    for(int j=0;j<4;++j){ int dk = (wc<<6)+(j<<4)+(lane&15); bfr[j] = *(const short8*)(Kb + (long)dk*N_ + tl); }
    #pragma unroll
    for(int i=0;i<4;++i)
      #pragma unroll
      for(int j=0;j<4;++j)
        acc[i][j] = __builtin_amdgcn_mfma_f32_16x16x32_bf16(af[i], bfr[j], acc[i][j], 0,0,0);
  }
  float dec = 1.f - exp2f(-5.f - (float)h);
  float scale = exp2f(127.f * log2f(dec));    // dec^{C-1}
  float* Mo = MS + ((long)bh*NC_ + c) * 16384;
  #pragma unroll
  for(int i=0;i<4;++i)
    #pragma unroll
    for(int j=0;j<4;++j)
      #pragma unroll
      for(int r=0;r<4;++r){
        int dv = (wr<<6)+(i<<4)+((lane>>4)<<2)+r;
        int dk = (wc<<6)+(j<<4)+(lane&15);
        Mo[dv*128 + dk] = acc[i][j][r] * scale;
      }
}

// ---------------- parallel scan over chunks (elementwise over state entries) ----------------
__global__ __launch_bounds__(256)
void k_scan(const float* __restrict__ MS, unsigned short* __restrict__ Scb,
            float* __restrict__ stateOut){
  int bid = blockIdx.x;
  int bh = bid >> 4, p = bid & 15;
  int tid = threadIdx.x, h = bh & 15;
  float dec = 1.f - exp2f(-5.f - (float)h);
  float decC = exp2f(128.f * log2f(dec));     // dec^C
  int e0 = p*1024 + tid*4;
  floatx4 S = {0.f, 0.f, 0.f, 0.f};
  const float* base = MS + (long)bh * NC_ * 16384 + e0;
  unsigned short* sb = Scb + (long)bh * NC_ * 16384 + e0;
  for(int c=0;c<NC_;++c){
    floatx4 m = *(const floatx4*)(base + (long)c*16384);
    short4v q;
    #pragma unroll
    for(int u=0;u<4;++u) q[u] = (short)f2bf(S[u]);
    *(short4v*)(sb + (long)c*16384) = q;
    S = decC * S + m;
  }
  // final state: element e = dv*128+dk (transposed layout) -> out [b][h][dk][dv]
  int dv = e0 >> 7, dk = e0 & 127;
  float* so = stateOut + (long)bh*16384 + dv;
  #pragma unroll
  for(int u=0;u<4;++u) so[(long)(dk+u)*128] = S[u];
}

// ---------------- retention output: masked decayed QK^T @ V + cross, group-norm, gate ----------------
__global__ __launch_bounds__(256)
void k_ret(const unsigned short* __restrict__ Y, const unsigned short* __restrict__ Vt,
           const unsigned short* __restrict__ Scb, unsigned short* __restrict__ RG){
  __shared__ unsigned short sQ[128*128];   // Qd = q * dec^t   (swizzled)
  __shared__ unsigned short sK[128*128];   // Kd = k * dec^-s ; reused for P
  int bid = blockIdx.x;
  int bh = bid >> 4, c = bid & 15, b = bh >> 4, h = bh & 15;
  int tid = threadIdx.x, w = tid >> 6, lane = tid & 63;
  float dec = 1.f - exp2f(-5.f - (float)h);
  float l2d = log2f(dec);

  #pragma unroll
  for(int p=0;p<8;++p){
    int t = p*16 + (tid>>4);
    long row = (long)(b*N_ + c*CH_ + t) * NCAT_ + h*128 + (tid&15)*8;
    short8 qv = *(const short8*)(Y + row);          // q section
    short8 kv = *(const short8*)(Y + row + 2048);   // k section
    float fq = exp2f((float)t * l2d);
    float fk = exp2f(-(float)t * l2d);
    short8 qs, ks;
    #pragma unroll
    for(int u=0;u<8;++u){
      qs[u] = (short)f2bf(bf2f((unsigned short)qv[u]) * fq);
      ks[u] = (short)f2bf(bf2f((unsigned short)kv[u]) * fk);
    }
    int ad = t*256 + (((tid&15)*16) ^ ((t&7)<<4));
    *(short8*)((char*)sQ + ad) = qs;
    *(short8*)((char*)sK + ad) = ks;
  }
  __syncthreads();

  floatx4 acc[2][8] = {};
  // QK^T (already includes dec^{t-s})
  #pragma unroll
  for(int kk=0;kk<4;++kk){
    int cb = (kk<<6) + ((lane>>4)<<4);
    short8 af[2], bfr[8];
    #pragma unroll
    for(int i=0;i<2;++i){ int t = w*32 + (i<<4) + (lane&15); af[i] = *(const short8*)((const char*)sQ + t*256 + (cb ^ ((t&7)<<4))); }
    #pragma unroll
    for(int j=0;j<8;++j){ int s = (j<<4) + (lane&15); bfr[j] = *(const short8*)((const char*)sK + s*256 + (cb ^ ((s&7)<<4))); }
    #pragma unroll
    for(int i=0;i<2;++i)
      #pragma unroll
      for(int j=0;j<8;++j)
        acc[i][j] = __builtin_amdgcn_mfma_f32_16x16x32_bf16(af[i], bfr[j], acc[i][j], 0,0,0);
  }
  __syncthreads();   // all waves done reading sK

  // causal mask, write P (bf16) into sK
  #pragma unroll
  for(int i=0;i<2;++i)
    #pragma unroll
    for(int j=0;j<8;++j)
      #pragma unroll
      for(int r=0;r<4;++r){
        int t = w*32 + (i<<4) + ((lane>>4)<<2) + r;
        int s = (j<<4) + (lane&15);
        float v = (s <= t) ? acc[i][j][r] : 0.f;
        *(unsigned short*)((char*)sK + t*256 + ((s*2) ^ ((t&7)<<4))) = f2bf(v);
      }
  __syncthreads();

  #pragma unroll
  for(int i=0;i<2;++i)
    #pragma unroll
    for(int j=0;j<8;++j)
      #pragma unroll
      for(int u=0;u<4;++u) acc[i][j][u] = 0.f;

  // ret = P @ V
  const unsigned short* Vb = Vt + (long)bh*128*N_ + c*CH_;
  #pragma unroll
  for(int kk=0;kk<4;++kk){
    int cb = (kk<<6) + ((lane>>4)<<4);
    int sg = kk*32 + ((lane>>4)<<3);
    short8 af[2], bfr[8];
    #pragma unroll
    for(int i=0;i<2;++i){ int t = w*32 + (i<<4) + (lane&15); af[i] = *(const short8*)((const char*)sK + t*256 + (cb ^ ((t&7)<<4))); }
    #pragma unroll
    for(int j=0;j<8;++j){ int dv = (j<<4) + (lane&15); bfr[j] = *(const short8*)(Vb + (long)dv*N_ + sg); }
    #pragma unroll
    for(int i=0;i<2;++i)
      #pragma unroll
      for(int j=0;j<8;++j)
        acc[i][j] = __builtin_amdgcn_mfma_f32_16x16x32_bf16(af[i], bfr[j], acc[i][j], 0,0,0);
  }
  // + dec^{t+1} * q @ S_c   (A = Qd*dec, B = Scb[dv][dk])
  const unsigned short* Sb = Scb + ((long)bh*NC_ + c) * 16384;
  #pragma unroll
  for(int kk=0;kk<4;++kk){
    int cb = (kk<<6) + ((lane>>4)<<4);
    int kg = kk*32 + ((lane>>4)<<3);
    short8 af[2], bfr[8];
    #pragma unroll
    for(int i=0;i<2;++i){
      int t = w*32 + (i<<4) + (lane&15);
      short8 qv = *(const short8*)((const char*)sQ + t*256 + (cb ^ ((t&7)<<4)));
      #pragma unroll
      for(int u=0;u<8;++u) af[i][u] = (short)f2bf(bf2f((unsigned short)qv[u]) * dec);
    }
    #pragma unroll
    for(int j=0;j<8;++j){ int dv = (j<<4) + (lane&15); bfr[j] = *(const short8*)(Sb + (long)dv*128 + kg); }
    #pragma unroll
    for(int i=0;i<2;++i)
      #pragma unroll
      for(int j=0;j<8;++j)
        acc[i][j] = __builtin_amdgcn_mfma_f32_16x16x32_bf16(af[i], bfr[j], acc[i][j], 0,0,0);
  }

  // group-norm over DV per row, gate, write bf16
  #pragma unroll
  for(int i=0;i<2;++i){
    #pragma unroll
    for(int r=0;r<4;++r){
      float s1 = 0.f, s2 = 0.f;
      #pragma unroll
      for(int j=0;j<8;++j){ float v = acc[i][j][r]; s1 += v; s2 += v*v; }
      #pragma unroll
      for(int off=1; off<16; off<<=1){ s1 += __shfl_xor(s1, off); s2 += __shfl_xor(s2, off); }
      float mu  = s1 * (1.f/128.f);
      float var = s2 * (1.f/128.f) - mu*mu;
      float inv = rsqrtf(var + 1e-6f);
      int t = w*32 + (i<<4) + ((lane>>4)<<2) + r;
      long mrow = (long)(b*N_ + c*CH_ + t);
      #pragma unroll
      for(int j=0;j<8;++j){
        int dv = (j<<4) + (lane&15);
        float v = (acc[i][j][r] - mu) * inv;
        float g = bf2f(Y[mrow*NCAT_ + 6144 + h*128 + dv]);
        RG[mrow*E_ + h*128 + dv] = f2bf(v * g);
      }
    }
  }
}

// ---------------- launch ----------------
extern "C" void kernel_launch(void* const* d_in, const int* in_sizes, int n_in,
                              void* d_out, int out_size, void* d_ws, size_t ws_size,
                              hipStream_t stream) {
  const float* x  = (const float*)d_in[0];
  const float* Wq = (const float*)d_in[1];
  const float* bq = (const float*)d_in[2];
  const float* Wk = (const float*)d_in[3];
  const float* bk = (const float*)d_in[4];
  const float* Wv = (const float*)d_in[5];
  const float* bv = (const float*)d_in[6];
  const float* Wg = (const float*)d_in[7];
  const float* bg = (const float*)d_in[8];
  const float* Wo = (const float*)d_in[9];
  const float* bo = (const float*)d_in[10];

  char* ws = (char*)d_ws;
  unsigned short* xb   = (unsigned short*)(ws + OFF_XB);
  unsigned short* Wcat = (unsigned short*)(ws + OFF_WCAT);
  unsigned short* Wob  = (unsigned short*)(ws + OFF_WOB);
  float*          bcat = (float*)(ws + OFF_BCAT);
  unsigned short* Y    = (unsigned short*)(ws + OFF_Y);
  unsigned short* Ktd  = (unsigned short*)(ws + OFF_KT);
  unsigned short* Vt   = (unsigned short*)(ws + OFF_VT);
  unsigned short* Scb  = (unsigned short*)(ws + OFF_SCB);
  float*          MS   = (float*)(ws + OFF_WCAT);   // reuse after GEMM1
  unsigned short* RG   = (unsigned short*)(ws + OFF_XB); // reuse after GEMM1

  float* outp     = (float*)d_out;
  float* stateOut = outp + (long)M_ * E_;   // 8,388,608

  // allow 128KB dynamic LDS for the 256^2 GEMM
  (void)hipFuncSetAttribute((const void*)k_gemm256,
                            hipFuncAttributeMaxDynamicSharedMemorySize, 131072);

  // fused prep (all casts + bias concat)
  k_castall<<<14340, 256, 0, stream>>>(x, Wq, Wk, Wv, Wg, Wo, bq, bk, bv, bg,
                                       xb, Wcat, Wob, bcat);

  // fused QKVG projection (256^2, quadrant-phase read-ahead)
  k_gemm256<<<512, 512, 131072, stream>>>(xb, Wcat, Y, bcat);

  // t-contiguous K (decay-weighted) and V
  k_transpose<<<1024, 256, 0, stream>>>(Y, Ktd, Vt);

  // retention
  k_chunksum<<<512, 256, 0, stream>>>(Ktd, Vt, MS);
  k_scan<<<512, 256, 0, stream>>>(MS, Scb, stateOut);
  k_ret<<<512, 256, 0, stream>>>(Y, Vt, Scb, RG);

  // output projection
  k_gemm<1><<<(M_/128)*(E_/128), 256, 0, stream>>>(RG, Wob, (void*)outp, bo, M_, E_, E_, E_/128);
}

// Round 8
// 281.122 us; speedup vs baseline: 1.2812x; 1.0063x over previous
//
#include <hip/hip_runtime.h>
#include <hip/hip_bf16.h>

typedef __attribute__((ext_vector_type(8))) short short8;
typedef __attribute__((ext_vector_type(4))) short short4v;
typedef __attribute__((ext_vector_type(4))) float floatx4;

#define DI __device__ __forceinline__

// Problem constants
constexpr int B_ = 2, N_ = 2048, H_ = 16, DK_ = 128, DV_ = 128, E_ = 2048;
constexpr int M_ = B_ * N_;          // 4096 token rows
constexpr int NCAT_ = 4 * E_;        // 8192 = q|k|v|g concat
constexpr int CH_ = 128;             // chunk length
constexpr int NC_ = N_ / CH_;        // 16 chunks
constexpr float KSCALE = 0.08838834764831845f; // 1/sqrt(128)

// Workspace layout (bytes)
constexpr long OFF_XB   = 0;                    // 16MB  bf16 x      (reused as RG after GEMM1)
constexpr long OFF_WCAT = 16777216;             // 32MB  bf16 Wq|Wk|Wv|Wg  (reused as MS f32 after GEMM1)
constexpr long OFF_WOB  = 50331648;             // 8MB   bf16 Wo
constexpr long OFF_BCAT = 58720256;             // 32KB  f32 concat bias
constexpr long OFF_Y    = 58753024;             // 64MB  bf16 [4096][8192] q|k|v|silu(g)
constexpr long OFF_KT   = 125861888;            // 16MB  bf16 Ktd [b][h][dk][t]  (k * dec^-(t%128))
constexpr long OFF_VT   = 142639104;            // 16MB  bf16 Vt  [b][h][dv][t]
constexpr long OFF_SCB  = 159416320;            // 16MB  bf16 per-chunk start states [bh][c][dv][dk]

DI unsigned short f2bf(float f){
  unsigned u = __float_as_uint(f);
  u += 0x7fffu + ((u >> 16) & 1u);
  return (unsigned short)(u >> 16);
}
DI float bf2f(unsigned short s){ return __uint_as_float(((unsigned)s) << 16); }

DI void gload_lds16(const void* g, void* l){
  __builtin_amdgcn_global_load_lds(
      (const __attribute__((address_space(1))) unsigned int*)g,
      (__attribute__((address_space(3))) unsigned int*)l, 16, 0, 0);
}

// ---------------- fused prep: all f32->bf16 casts + bias concat ----------------
__global__ void k_castall(const float* __restrict__ x,
                          const float* __restrict__ Wq, const float* __restrict__ Wk,
                          const float* __restrict__ Wv, const float* __restrict__ Wg,
                          const float* __restrict__ Wo,
                          const float* __restrict__ bq, const float* __restrict__ bk,
                          const float* __restrict__ bv, const float* __restrict__ bg,
                          unsigned short* __restrict__ xb, unsigned short* __restrict__ Wcat,
                          unsigned short* __restrict__ Wob, float* __restrict__ bcat){
  int bid = blockIdx.x;
  if(bid >= 14336){
    int i = (bid - 14336) * 2048 + threadIdx.x * 8;
    #pragma unroll
    for(int u=0;u<8;++u){
      int j = i + u;
      float v;
      if(j < 2048)      v = bq[j];
      else if(j < 4096) v = bk[j - 2048];
      else if(j < 6144) v = bv[j - 4096];
      else              v = bg[j - 6144];
      bcat[j] = v;
    }
    return;
  }
  const float* s; unsigned short* d; long off;
  if(bid < 4096){ s = x; d = xb; off = (long)bid*2048; }
  else if(bid < 6144){ s = Wq; d = Wcat;            off = (long)(bid-4096)*2048; }
  else if(bid < 8192){ s = Wk; d = Wcat + 4194304L; off = (long)(bid-6144)*2048; }
  else if(bid < 10240){ s = Wv; d = Wcat + 8388608L; off = (long)(bid-8192)*2048; }
  else if(bid < 12288){ s = Wg; d = Wcat + 12582912L; off = (long)(bid-10240)*2048; }
  else { s = Wo; d = Wob; off = (long)(bid-12288)*2048; }
  long i = off + (long)threadIdx.x * 8;
  float4 v0 = *(const float4*)(s + i);
  float4 v1 = *(const float4*)(s + i + 4);
  short8 o;
  o[0]=(short)f2bf(v0.x); o[1]=(short)f2bf(v0.y); o[2]=(short)f2bf(v0.z); o[3]=(short)f2bf(v0.w);
  o[4]=(short)f2bf(v1.x); o[5]=(short)f2bf(v1.y); o[6]=(short)f2bf(v1.z); o[7]=(short)f2bf(v1.w);
  *(short8*)(d + i) = o;
}

// ================= 256x256 GEMM, m201-faithful 8-phase schedule =================
// 512 threads = 8 waves (2M x 4N), wave tile 128x64, BK=64, 128KB LDS dbuf.
// 8 phases per 2 K-tiles; per K-tile quadrant order Q00,Q01,Q11,Q10 with
// operand-register reuse (12/4/8/0 ds_reads per phase). PER-WAVE-SPECIALIZED
// staging: each wave stages only the LDS bands it will itself consume, so its
// vmcnt counter tracks exactly its own data; uniform counted s_waitcnt vmcnt(4)
// per phase (never a drain), >=3 phases (~1800cy) flight per staged band.
// Phase = [ds_reads][stage 0-4 gloads][vmcnt(4)][bar][setprio+16 MFMA][bar].
__global__ __launch_bounds__(512, 2)
void k_gemm256(const unsigned short* __restrict__ A,
               const unsigned short* __restrict__ Bt,
               unsigned short* __restrict__ Y,
               const float* __restrict__ bias)
{
  extern __shared__ unsigned short lds[];   // A: [0,32768) shorts; B: [32768,65536) shorts; x2 bufs inside
  constexpr int K = 2048;
  constexpr int NKT = K / 64;               // 32

  const int tid = threadIdx.x;
  const int wave = tid >> 6, lane = tid & 63;
  const int wr = wave >> 2, wc = wave & 3;
  const int l15 = lane & 15;

  // XCD-bijective 8x8 supertile swizzle
  int bid = blockIdx.x;
  int g = bid & 7, w = bid >> 3;
  int bm = (g & 1) * 8 + (w & 7);           // 0..15
  int bn = (g >> 1) * 8 + (w >> 3);         // 0..31

  const unsigned short* Ag = A  + (long)bm * 256 * K;
  const unsigned short* Bg = Bt + (long)bn * 256 * K;

  // staging geometry: 8-row gload blocks; row-in-block sr, pre-swizzled col sc
  const int sr = (lane >> 3);
  const int sc = ((lane & 7) ^ sr) * 8;
  // read col swizzle: chunk c = kk*4 + (lane>>4), position = c ^ (row&7), row&7 == lane&7
  const int colx[2] = { ((0 + (lane>>4)) ^ (lane&7)) << 4,
                        ((4 + (lane>>4)) ^ (lane&7)) << 4 };

  floatx4 acc[8][4] = {};     // [mh*4+ai][nh*2+bj]
  const char* ldsc = (const char*)lds;
  short8 Aa[8], Ab[8], Ba[4], Bb[4];   // persistent operand slots (96 VGPR)

  // ---- per-wave-owned staging ----
  // A band (mh): rows wr*128 + mh*64 + wc*16 + g*8 + sr  (4 waves of same wr cover the band)
  // LDS A(buf, half=wr): buf*16384 + wr*8192 shorts, row-major [128][64]
#define STG_A(buf, kt, mh) do{                                                        \
    _Pragma("unroll")                                                                 \
    for(int g2=0; g2<2; ++g2){                                                        \
      gload_lds16(Ag + (long)(wr*128 + (mh)*64 + wc*16 + g2*8 + sr)*K                 \
                     + (long)(kt)*64 + sc,                                            \
                  &lds[(buf)*16384 + wr*8192 + ((mh)*64 + wc*16 + g2*8)*64 + lane*8]);\
    }                                                                                 \
  }while(0)

  // B band (nh): N-rows bn*256 + wc*64 + nh*32 + wr*16 + g*8 + sr (2 waves of same wc)
  // LDS B(buf, half=wc>>1): 32768 + buf*16384 + (wc>>1)*8192, row-in-half = (wc&1)*64 + nh*32 + ...
#define STG_B(buf, kt, nh) do{                                                        \
    _Pragma("unroll")                                                                 \
    for(int g2=0; g2<2; ++g2){                                                        \
      gload_lds16(Bg + (long)(wc*64 + (nh)*32 + wr*16 + g2*8 + sr)*K                  \
                     + (long)(kt)*64 + sc,                                            \
                  &lds[32768 + (buf)*16384 + (wc>>1)*8192                             \
                       + ((wc&1)*64 + (nh)*32 + wr*16 + g2*8)*64 + lane*8]);          \
    }                                                                                 \
  }while(0)

#define RD_A(dst, buf, mh) do{                                                        \
    const char* _b = ldsc + ((buf)*16384 + wr*8192)*2;                                \
    _Pragma("unroll")                                                                 \
    for(int ai=0; ai<4; ++ai){                                                        \
      const int _rb = ((mh)*64 + ai*16 + l15) << 7;                                   \
      dst[ai*2+0] = *(const short8*)(_b + _rb + colx[0]);                             \
      dst[ai*2+1] = *(const short8*)(_b + _rb + colx[1]);                             \
    }                                                                                 \
  }while(0)

#define RD_B(dst, buf, nh) do{                                                        \
    const char* _b = ldsc + (32768 + (buf)*16384 + (wc>>1)*8192)*2;                   \
    _Pragma("unroll")                                                                 \
    for(int bj=0; bj<2; ++bj){                                                        \
      const int _rb = ((wc&1)*64 + (nh)*32 + bj*16 + l15) << 7;                       \
      dst[bj*2+0] = *(const short8*)(_b + _rb + colx[0]);                             \
      dst[bj*2+1] = *(const short8*)(_b + _rb + colx[1]);                             \
    }                                                                                 \
  }while(0)

#define MFQ(mh, nh, As, Bs) do{                                                       \
    __builtin_amdgcn_s_setprio(1);                                                    \
    _Pragma("unroll")                                                                 \
    for(int ai=0; ai<4; ++ai)                                                         \
      _Pragma("unroll")                                                               \
      for(int bj=0; bj<2; ++bj)                                                       \
        _Pragma("unroll")                                                             \
        for(int kk=0; kk<2; ++kk)                                                     \
          acc[(mh)*4+ai][(nh)*2+bj] = __builtin_amdgcn_mfma_f32_16x16x32_bf16(        \
              As[ai*2+kk], Bs[bj*2+kk], acc[(mh)*4+ai][(nh)*2+bj], 0,0,0);            \
    __builtin_amdgcn_s_setprio(0);                                                    \
  }while(0)

#define VM4   asm volatile("s_waitcnt vmcnt(4)" ::: "memory")
#define BAR   __builtin_amdgcn_s_barrier()
#define SCHED __builtin_amdgcn_sched_barrier(0)

  // prologue: tile0 -> buf0, band order A0,B0,B1,A1; drain A0,B0 before loop
  STG_A(0, 0, 0); STG_B(0, 0, 0); STG_B(0, 0, 1); STG_A(0, 0, 1);
  VM4;    // drains A0,B0 (leaves B1,A1)
  BAR;
  SCHED;

  #pragma unroll 1
  for(int i=0; i<NKT/2; ++i){
    const int t1 = 2*i + 1;
    const int t2 = (2*i + 2) & (NKT - 1);

    // ---- tile 2i (buf0); stage tile 2i+1 -> buf1 ----
    // p1: Q00
    RD_A(Aa, 0, 0); RD_B(Ba, 0, 0);
    STG_A(1, t1, 0); STG_B(1, t1, 0);
    VM4; BAR;
    MFQ(0, 0, Aa, Ba);
    BAR; SCHED;
    // p2: Q01
    RD_B(Bb, 0, 1);
    STG_B(1, t1, 1);
    VM4; BAR;
    MFQ(0, 1, Aa, Bb);
    BAR; SCHED;
    // p3: Q11
    RD_A(Ab, 0, 1);
    STG_A(1, t1, 1);
    VM4; BAR;
    MFQ(1, 1, Ab, Bb);
    BAR; SCHED;
    // p4: Q10 (pure MFMA)
    VM4; BAR;
    MFQ(1, 0, Ab, Ba);
    BAR; SCHED;

    // ---- tile 2i+1 (buf1); stage tile 2i+2 -> buf0 ----
    // p5: Q00
    RD_A(Aa, 1, 0); RD_B(Ba, 1, 0);
    STG_A(0, t2, 0); STG_B(0, t2, 0);
    VM4; BAR;
    MFQ(0, 0, Aa, Ba);
    BAR; SCHED;
    // p6: Q01
    RD_B(Bb, 1, 1);
    STG_B(0, t2, 1);
    VM4; BAR;
    MFQ(0, 1, Aa, Bb);
    BAR; SCHED;
    // p7: Q11
    RD_A(Ab, 1, 1);
    STG_A(0, t2, 1);
    VM4; BAR;
    MFQ(1, 1, Ab, Bb);
    BAR; SCHED;
    // p8: Q10 (pure MFMA)
    VM4; BAR;
    MFQ(1, 0, Ab, Ba);
    BAR; SCHED;
  }
#undef STG_A
#undef STG_B
#undef RD_A
#undef RD_B
#undef MFQ
#undef VM4
#undef BAR
#undef SCHED

  // epilogue: bias + section transforms, bf16 store
  #pragma unroll
  for(int mh=0;mh<2;++mh){
    #pragma unroll
    for(int ai=0;ai<4;++ai){
      const int rowi = bm*256 + wr*128 + mh*64 + ai*16 + ((lane>>4)<<2);
      #pragma unroll
      for(int nh=0;nh<2;++nh){
        #pragma unroll
        for(int bj=0;bj<2;++bj){
          const int col = bn*256 + wc*64 + nh*32 + bj*16 + l15;
          const float bs = bias[col];
          const int sec = col >> 11;
          #pragma unroll
          for(int r=0;r<4;++r){
            float v = acc[mh*4+ai][nh*2+bj][r] + bs;
            if(sec == 1) v *= KSCALE;
            else if(sec == 3) v = v / (1.f + __expf(-v));   // silu
            Y[(long)(rowi + r) * NCAT_ + col] = f2bf(v);
          }
        }
      }
    }
  }
}

// ---------------- 128^2 GEMM, flat-pipelined double-buffer (output projection) ----------------
template<int EPI>
__global__ __launch_bounds__(256)
void k_gemm(const unsigned short* __restrict__ A,
            const unsigned short* __restrict__ Bt,
            void* __restrict__ outp,
            const float* __restrict__ bias,
            int M, int Ncols, int K, int NB)
{
  __shared__ unsigned short lA[2*128*64];
  __shared__ unsigned short lB[2*128*64];
  const int bid = blockIdx.x;
  const int bm = bid / NB, bn = bid % NB;
  const int tid = threadIdx.x;
  const int wave = tid >> 6, lane = tid & 63;
  const int wr = wave >> 1, wc = wave & 1;

  floatx4 acc[4][4] = {};

  int srow[4], scol[4];
  #pragma unroll
  for(int is=0; is<4; ++is){
    int o = is*4096 + wave*1024 + lane*16;     // byte offset in 16KB tile
    int row = o >> 7;
    int logcb = (o & 127) ^ ((row & 7) << 4);  // inverse-swizzled source column
    srow[is] = row; scol[is] = logcb >> 1;
  }
  const unsigned short* Abase = A + (long)bm * 128 * K;
  const unsigned short* Bbase = Bt + (long)bn * 128 * K;

#define STG128(kt, buf) do{                                                          \
    const int _k0 = (kt) << 6;                                                       \
    _Pragma("unroll")                                                                \
    for(int is=0; is<4; ++is){                                                       \
      gload_lds16(Abase + (long)srow[is]*K + _k0 + scol[is], &lA[(buf)*8192 + ((is*4096 + wave*1024) >> 1)]); \
      gload_lds16(Bbase + (long)srow[is]*K + _k0 + scol[is], &lB[(buf)*8192 + ((is*4096 + wave*1024) >> 1)]); \
    }                                                                                \
  }while(0)

  const int nkt = K >> 6;
  STG128(0, 0);
  for(int kt=0; kt<nkt; ++kt){
    const int cur = kt & 1, nxt = cur ^ 1;
    const int ktn = (kt + 1 == nkt) ? 0 : kt + 1;
    __syncthreads();
    STG128(ktn, nxt);
    const char* cA = (const char*)lA + cur*16384;
    const char* cB = (const char*)lB + cur*16384;
    #pragma unroll
    for(int kk=0; kk<2; ++kk){
      const int cb = (kk<<6) + ((lane>>4)<<4);
      short8 af[4], bfr[4];
      #pragma unroll
      for(int i=0;i<4;++i){
        int row = (wr<<6) + (i<<4) + (lane&15);
        af[i] = *(const short8*)(cA + (row<<7) + (cb ^ ((row&7)<<4)));
      }
      #pragma unroll
      for(int j=0;j<4;++j){
        int row = (wc<<6) + (j<<4) + (lane&15);
        bfr[j] = *(const short8*)(cB + (row<<7) + (cb ^ ((row&7)<<4)));
      }
      #pragma unroll
      for(int i=0;i<4;++i)
        #pragma unroll
        for(int j=0;j<4;++j)
          acc[i][j] = __builtin_amdgcn_mfma_f32_16x16x32_bf16(af[i], bfr[j], acc[i][j], 0,0,0);
    }
  }
#undef STG128

  #pragma unroll
  for(int i=0;i<4;++i){
    #pragma unroll
    for(int j=0;j<4;++j){
      #pragma unroll
      for(int r=0;r<4;++r){
        int row = bm*128 + (wr<<6) + (i<<4) + ((lane>>4)<<2) + r;
        int col = bn*128 + (wc<<6) + (j<<4) + (lane&15);
        float v = acc[i][j][r] + bias[col];
        if(EPI == 0){
          int sec = col >> 11;
          if(sec == 1) v *= KSCALE;
          else if(sec == 3) v = v / (1.f + __expf(-v));   // silu
          ((unsigned short*)outp)[(long)row * Ncols + col] = f2bf(v);
        } else {
          ((float*)outp)[(long)row * Ncols + col] = v;
        }
      }
    }
  }
}

// ---------------- transpose K,V to t-contiguous; bake dec^-(t%128) into K ----------------
__global__ __launch_bounds__(256)
void k_transpose(const unsigned short* __restrict__ Y,
                 unsigned short* __restrict__ Kt, unsigned short* __restrict__ Vt){
  __shared__ unsigned short lt[128][136];
  int bid = blockIdx.x;
  int op = bid >> 9;            // 0: K, 1: V
  int r  = bid & 511;
  int bh = r >> 4, c = r & 15, b = bh >> 4, h = bh & 15;
  int tid = threadIdx.x;
  float dec = 1.f - exp2f(-5.f - (float)h);
  float l2d = log2f(dec);
  int sec = op ? 4096 : 2048;
  unsigned short* Dst = op ? Vt : Kt;

  #pragma unroll
  for(int p=0;p<8;++p){
    int t = p*16 + (tid>>4);
    long src = ((long)(b*N_ + c*CH_ + t)) * NCAT_ + sec + h*128 + (tid&15)*8;
    short8 v = *(const short8*)(Y + src);
    if(op == 0){
      float f = exp2f(-(float)t * l2d);   // dec^{-t}
      #pragma unroll
      for(int u=0;u<8;++u) v[u] = (short)f2bf(bf2f((unsigned short)v[u]) * f);
    }
    *(short8*)&lt[t][(tid&15)*8] = v;
  }
  __syncthreads();
  #pragma unroll
  for(int p=0;p<8;++p){
    int dk = p*16 + (tid>>4);
    int tc = (tid&15)*8;
    short8 o;
    #pragma unroll
    for(int u=0;u<8;++u) o[u] = (short)lt[tc+u][dk];
    *(short8*)(Dst + ((long)(bh*128 + dk)) * N_ + c*CH_ + tc) = o;
  }
}

// ---------------- per-chunk summary Mt_c[dv][dk] = dec^{C-1} * sum_t Vt[dv][t]*Ktd[dk][t] ----------------
__global__ __launch_bounds__(256)
void k_chunksum(const unsigned short* __restrict__ Ktd, const unsigned short* __restrict__ Vt,
                float* __restrict__ MS){
  int bid = blockIdx.x;            // 512: bh*16 + c
  int bh = bid >> 4, c = bid & 15, h = bh & 15;
  int tid = threadIdx.x, wave = tid >> 6, lane = tid & 63;
  int wr = wave >> 1, wc = wave & 1;
  floatx4 acc[4][4] = {};
  const unsigned short* Vb = Vt  + (long)bh*128*N_ + c*CH_;
  const unsigned short* Kb = Ktd + (long)bh*128*N_ + c*CH_;

  #pragma unroll
  for(int kk=0;kk<4;++kk){
    int tl = kk*32 + ((lane>>4)<<3);
    short8 af[4], bfr[4];
    #pragma unroll
    for(int i=0;i<4;++i){ int dv = (wr<<6)+(i<<4)+(lane&15); af[i]  = *(const short8*)(Vb + (long)dv*N_ + tl); }
    #pragma unroll
    for(int j=0;j<4;++j){ int dk = (wc<<6)+(j<<4)+(lane&15); bfr[j] = *(const short8*)(Kb + (long)dk*N_ + tl); }
    #pragma unroll
    for(int i=0;i<4;++i)
      #pragma unroll
      for(int j=0;j<4;++j)
        acc[i][j] = __builtin_amdgcn_mfma_f32_16x16x32_bf16(af[i], bfr[j], acc[i][j], 0,0,0);
  }
  float dec = 1.f - exp2f(-5.f - (float)h);
  float scale = exp2f(127.f * log2f(dec));    // dec^{C-1}
  float* Mo = MS + ((long)bh*NC_ + c) * 16384;
  #pragma unroll
  for(int i=0;i<4;++i)
    #pragma unroll
    for(int j=0;j<4;++j)
      #pragma unroll
      for(int r=0;r<4;++r){
        int dv = (wr<<6)+(i<<4)+((lane>>4)<<2)+r;
        int dk = (wc<<6)+(j<<4)+(lane&15);
        Mo[dv*128 + dk] = acc[i][j][r] * scale;
      }
}

// ---------------- parallel scan over chunks (elementwise over state entries) ----------------
__global__ __launch_bounds__(256)
void k_scan(const float* __restrict__ MS, unsigned short* __restrict__ Scb,
            float* __restrict__ stateOut){
  int bid = blockIdx.x;
  int bh = bid >> 4, p = bid & 15;
  int tid = threadIdx.x, h = bh & 15;
  float dec = 1.f - exp2f(-5.f - (float)h);
  float decC = exp2f(128.f * log2f(dec));     // dec^C
  int e0 = p*1024 + tid*4;
  floatx4 S = {0.f, 0.f, 0.f, 0.f};
  const float* base = MS + (long)bh * NC_ * 16384 + e0;
  unsigned short* sb = Scb + (long)bh * NC_ * 16384 + e0;
  for(int c=0;c<NC_;++c){
    floatx4 m = *(const floatx4*)(base + (long)c*16384);
    short4v q;
    #pragma unroll
    for(int u=0;u<4;++u) q[u] = (short)f2bf(S[u]);
    *(short4v*)(sb + (long)c*16384) = q;
    S = decC * S + m;
  }
  // final state: element e = dv*128+dk (transposed layout) -> out [b][h][dk][dv]
  int dv = e0 >> 7, dk = e0 & 127;
  float* so = stateOut + (long)bh*16384 + dv;
  #pragma unroll
  for(int u=0;u<4;++u) so[(long)(dk+u)*128] = S[u];
}

// ---------------- retention output: masked decayed QK^T @ V + cross, group-norm, gate ----------------
__global__ __launch_bounds__(256)
void k_ret(const unsigned short* __restrict__ Y, const unsigned short* __restrict__ Vt,
           const unsigned short* __restrict__ Scb, unsigned short* __restrict__ RG){
  __shared__ unsigned short sQ[128*128];   // Qd = q * dec^t   (swizzled)
  __shared__ unsigned short sK[128*128];   // Kd = k * dec^-s ; reused for P
  int bid = blockIdx.x;
  int bh = bid >> 4, c = bid & 15, b = bh >> 4, h = bh & 15;
  int tid = threadIdx.x, w = tid >> 6, lane = tid & 63;
  float dec = 1.f - exp2f(-5.f - (float)h);
  float l2d = log2f(dec);

  #pragma unroll
  for(int p=0;p<8;++p){
    int t = p*16 + (tid>>4);
    long row = (long)(b*N_ + c*CH_ + t) * NCAT_ + h*128 + (tid&15)*8;
    short8 qv = *(const short8*)(Y + row);          // q section
    short8 kv = *(const short8*)(Y + row + 2048);   // k section
    float fq = exp2f((float)t * l2d);
    float fk = exp2f(-(float)t * l2d);
    short8 qs, ks;
    #pragma unroll
    for(int u=0;u<8;++u){
      qs[u] = (short)f2bf(bf2f((unsigned short)qv[u]) * fq);
      ks[u] = (short)f2bf(bf2f((unsigned short)kv[u]) * fk);
    }
    int ad = t*256 + (((tid&15)*16) ^ ((t&7)<<4));
    *(short8*)((char*)sQ + ad) = qs;
    *(short8*)((char*)sK + ad) = ks;
  }
  __syncthreads();

  floatx4 acc[2][8] = {};
  // QK^T (already includes dec^{t-s})
  #pragma unroll
  for(int kk=0;kk<4;++kk){
    int cb = (kk<<6) + ((lane>>4)<<4);
    short8 af[2], bfr[8];
    #pragma unroll
    for(int i=0;i<2;++i){ int t = w*32 + (i<<4) + (lane&15); af[i] = *(const short8*)((const char*)sQ + t*256 + (cb ^ ((t&7)<<4))); }
    #pragma unroll
    for(int j=0;j<8;++j){ int s = (j<<4) + (lane&15); bfr[j] = *(const short8*)((const char*)sK + s*256 + (cb ^ ((s&7)<<4))); }
    #pragma unroll
    for(int i=0;i<2;++i)
      #pragma unroll
      for(int j=0;j<8;++j)
        acc[i][j] = __builtin_amdgcn_mfma_f32_16x16x32_bf16(af[i], bfr[j], acc[i][j], 0,0,0);
  }
  __syncthreads();   // all waves done reading sK

  // causal mask, write P (bf16) into sK
  #pragma unroll
  for(int i=0;i<2;++i)
    #pragma unroll
    for(int j=0;j<8;++j)
      #pragma unroll
      for(int r=0;r<4;++r){
        int t = w*32 + (i<<4) + ((lane>>4)<<2) + r;
        int s = (j<<4) + (lane&15);
        float v = (s <= t) ? acc[i][j][r] : 0.f;
        *(unsigned short*)((char*)sK + t*256 + ((s*2) ^ ((t&7)<<4))) = f2bf(v);
      }
  __syncthreads();

  #pragma unroll
  for(int i=0;i<2;++i)
    #pragma unroll
    for(int j=0;j<8;++j)
      #pragma unroll
      for(int u=0;u<4;++u) acc[i][j][u] = 0.f;

  // ret = P @ V
  const unsigned short* Vb = Vt + (long)bh*128*N_ + c*CH_;
  #pragma unroll
  for(int kk=0;kk<4;++kk){
    int cb = (kk<<6) + ((lane>>4)<<4);
    int sg = kk*32 + ((lane>>4)<<3);
    short8 af[2], bfr[8];
    #pragma unroll
    for(int i=0;i<2;++i){ int t = w*32 + (i<<4) + (lane&15); af[i] = *(const short8*)((const char*)sK + t*256 + (cb ^ ((t&7)<<4))); }
    #pragma unroll
    for(int j=0;j<8;++j){ int dv = (j<<4) + (lane&15); bfr[j] = *(const short8*)(Vb + (long)dv*N_ + sg); }
    #pragma unroll
    for(int i=0;i<2;++i)
      #pragma unroll
      for(int j=0;j<8;++j)
        acc[i][j] = __builtin_amdgcn_mfma_f32_16x16x32_bf16(af[i], bfr[j], acc[i][j], 0,0,0);
  }
  // + dec^{t+1} * q @ S_c   (A = Qd*dec, B = Scb[dv][dk])
  const unsigned short* Sb = Scb + ((long)bh*NC_ + c) * 16384;
  #pragma unroll
  for(int kk=0;kk<4;++kk){
    int cb = (kk<<6) + ((lane>>4)<<4);
    int kg = kk*32 + ((lane>>4)<<3);
    short8 af[2], bfr[8];
    #pragma unroll
    for(int i=0;i<2;++i){
      int t = w*32 + (i<<4) + (lane&15);
      short8 qv = *(const short8*)((const char*)sQ + t*256 + (cb ^ ((t&7)<<4)));
      #pragma unroll
      for(int u=0;u<8;++u) af[i][u] = (short)f2bf(bf2f((unsigned short)qv[u]) * dec);
    }
    #pragma unroll
    for(int j=0;j<8;++j){ int dv = (j<<4) + (lane&15); bfr[j] = *(const short8*)(Sb + (long)dv*128 + kg); }
    #pragma unroll
    for(int i=0;i<2;++i)
      #pragma unroll
      for(int j=0;j<8;++j)
        acc[i][j] = __builtin_amdgcn_mfma_f32_16x16x32_bf16(af[i], bfr[j], acc[i][j], 0,0,0);
  }

  // group-norm over DV per row, gate, write bf16
  #pragma unroll
  for(int i=0;i<2;++i){
    #pragma unroll
    for(int r=0;r<4;++r){
      float s1 = 0.f, s2 = 0.f;
      #pragma unroll
      for(int j=0;j<8;++j){ float v = acc[i][j][r]; s1 += v; s2 += v*v; }
      #pragma unroll
      for(int off=1; off<16; off<<=1){ s1 += __shfl_xor(s1, off); s2 += __shfl_xor(s2, off); }
      float mu  = s1 * (1.f/128.f);
      float var = s2 * (1.f/128.f) - mu*mu;
      float inv = rsqrtf(var + 1e-6f);
      int t = w*32 + (i<<4) + ((lane>>4)<<2) + r;
      long mrow = (long)(b*N_ + c*CH_ + t);
      #pragma unroll
      for(int j=0;j<8;++j){
        int dv = (j<<4) + (lane&15);
        float v = (acc[i][j][r] - mu) * inv;
        float g = bf2f(Y[mrow*NCAT_ + 6144 + h*128 + dv]);
        RG[mrow*E_ + h*128 + dv] = f2bf(v * g);
      }
    }
  }
}

// ---------------- launch ----------------
extern "C" void kernel_launch(void* const* d_in, const int* in_sizes, int n_in,
                              void* d_out, int out_size, void* d_ws, size_t ws_size,
                              hipStream_t stream) {
  const float* x  = (const float*)d_in[0];
  const float* Wq = (const float*)d_in[1];
  const float* bq = (const float*)d_in[2];
  const float* Wk = (const float*)d_in[3];
  const float* bk = (const float*)d_in[4];
  const float* Wv = (const float*)d_in[5];
  const float* bv = (const float*)d_in[6];
  const float* Wg = (const float*)d_in[7];
  const float* bg = (const float*)d_in[8];
  const float* Wo = (const float*)d_in[9];
  const float* bo = (const float*)d_in[10];

  char* ws = (char*)d_ws;
  unsigned short* xb   = (unsigned short*)(ws + OFF_XB);
  unsigned short* Wcat = (unsigned short*)(ws + OFF_WCAT);
  unsigned short* Wob  = (unsigned short*)(ws + OFF_WOB);
  float*          bcat = (float*)(ws + OFF_BCAT);
  unsigned short* Y    = (unsigned short*)(ws + OFF_Y);
  unsigned short* Ktd  = (unsigned short*)(ws + OFF_KT);
  unsigned short* Vt   = (unsigned short*)(ws + OFF_VT);
  unsigned short* Scb  = (unsigned short*)(ws + OFF_SCB);
  float*          MS   = (float*)(ws + OFF_WCAT);   // reuse after GEMM1
  unsigned short* RG   = (unsigned short*)(ws + OFF_XB); // reuse after GEMM1

  float* outp     = (float*)d_out;
  float* stateOut = outp + (long)M_ * E_;   // 8,388,608

  // allow 128KB dynamic LDS for the 256^2 GEMM
  (void)hipFuncSetAttribute((const void*)k_gemm256,
                            hipFuncAttributeMaxDynamicSharedMemorySize, 131072);

  // fused prep (all casts + bias concat)
  k_castall<<<14340, 256, 0, stream>>>(x, Wq, Wk, Wv, Wg, Wo, bq, bk, bv, bg,
                                       xb, Wcat, Wob, bcat);

  // fused QKVG projection (256^2, m201-faithful 8-phase)
  k_gemm256<<<512, 512, 131072, stream>>>(xb, Wcat, Y, bcat);

  // t-contiguous K (decay-weighted) and V
  k_transpose<<<1024, 256, 0, stream>>>(Y, Ktd, Vt);

  // retention
  k_chunksum<<<512, 256, 0, stream>>>(Ktd, Vt, MS);
  k_scan<<<512, 256, 0, stream>>>(MS, Scb, stateOut);
  k_ret<<<512, 256, 0, stream>>>(Y, Vt, Scb, RG);

  // output projection
  k_gemm<1><<<(M_/128)*(E_/128), 256, 0, stream>>>(RG, Wob, (void*)outp, bo, M_, E_, E_, E_/128);
}

// Round 9
// 261.295 us; speedup vs baseline: 1.3784x; 1.0759x over previous
//
#include <hip/hip_runtime.h>
#include <hip/hip_bf16.h>

typedef __attribute__((ext_vector_type(8))) short short8;
typedef __attribute__((ext_vector_type(4))) short short4v;
typedef __attribute__((ext_vector_type(4))) float floatx4;

#define DI __device__ __forceinline__

// Problem constants
constexpr int B_ = 2, N_ = 2048, H_ = 16, DK_ = 128, DV_ = 128, E_ = 2048;
constexpr int M_ = B_ * N_;          // 4096 token rows
constexpr int NCAT_ = 4 * E_;        // 8192 = q|k|v|g concat
constexpr int CH_ = 128;             // chunk length
constexpr int NC_ = N_ / CH_;        // 16 chunks
constexpr float KSCALE = 0.08838834764831845f; // 1/sqrt(128)

// Workspace layout (bytes)
constexpr long OFF_XB   = 0;                    // 16MB  bf16 x      (reused as RG after GEMM1)
constexpr long OFF_WCAT = 16777216;             // 32MB  bf16 Wq|Wk|Wv|Wg  (reused as MS f32 after GEMM1)
constexpr long OFF_WOB  = 50331648;             // 8MB   bf16 Wo
constexpr long OFF_BCAT = 58720256;             // 32KB  f32 concat bias
constexpr long OFF_Y    = 58753024;             // 64MB  bf16 [4096][8192] q|k|v|silu(g)
constexpr long OFF_KT   = 125861888;            // (unused now)
constexpr long OFF_VT   = 142639104;            // 16MB  bf16 Vt  [b][h][dv][t]
constexpr long OFF_SCB  = 159416320;            // 16MB  bf16 per-chunk start states [bh][c][dv][dk]

DI unsigned short f2bf(float f){
  unsigned u = __float_as_uint(f);
  u += 0x7fffu + ((u >> 16) & 1u);
  return (unsigned short)(u >> 16);
}
DI float bf2f(unsigned short s){ return __uint_as_float(((unsigned)s) << 16); }

DI void gload_lds16(const void* g, void* l){
  __builtin_amdgcn_global_load_lds(
      (const __attribute__((address_space(1))) unsigned int*)g,
      (__attribute__((address_space(3))) unsigned int*)l, 16, 0, 0);
}

// ---------------- fused prep: all f32->bf16 casts + bias concat ----------------
__global__ void k_castall(const float* __restrict__ x,
                          const float* __restrict__ Wq, const float* __restrict__ Wk,
                          const float* __restrict__ Wv, const float* __restrict__ Wg,
                          const float* __restrict__ Wo,
                          const float* __restrict__ bq, const float* __restrict__ bk,
                          const float* __restrict__ bv, const float* __restrict__ bg,
                          unsigned short* __restrict__ xb, unsigned short* __restrict__ Wcat,
                          unsigned short* __restrict__ Wob, float* __restrict__ bcat){
  int bid = blockIdx.x;
  if(bid >= 14336){
    int i = (bid - 14336) * 2048 + threadIdx.x * 8;
    #pragma unroll
    for(int u=0;u<8;++u){
      int j = i + u;
      float v;
      if(j < 2048)      v = bq[j];
      else if(j < 4096) v = bk[j - 2048];
      else if(j < 6144) v = bv[j - 4096];
      else              v = bg[j - 6144];
      bcat[j] = v;
    }
    return;
  }
  const float* s; unsigned short* d; long off;
  if(bid < 4096){ s = x; d = xb; off = (long)bid*2048; }
  else if(bid < 6144){ s = Wq; d = Wcat;            off = (long)(bid-4096)*2048; }
  else if(bid < 8192){ s = Wk; d = Wcat + 4194304L; off = (long)(bid-6144)*2048; }
  else if(bid < 10240){ s = Wv; d = Wcat + 8388608L; off = (long)(bid-8192)*2048; }
  else if(bid < 12288){ s = Wg; d = Wcat + 12582912L; off = (long)(bid-10240)*2048; }
  else { s = Wo; d = Wob; off = (long)(bid-12288)*2048; }
  long i = off + (long)threadIdx.x * 8;
  float4 v0 = *(const float4*)(s + i);
  float4 v1 = *(const float4*)(s + i + 4);
  short8 o;
  o[0]=(short)f2bf(v0.x); o[1]=(short)f2bf(v0.y); o[2]=(short)f2bf(v0.z); o[3]=(short)f2bf(v0.w);
  o[4]=(short)f2bf(v1.x); o[5]=(short)f2bf(v1.y); o[6]=(short)f2bf(v1.z); o[7]=(short)f2bf(v1.w);
  *(short8*)(d + i) = o;
}

// ================= 256x256 GEMM, m201-style 8-phase schedule (R8 version, kept) =================
__global__ __launch_bounds__(512, 2)
void k_gemm256(const unsigned short* __restrict__ A,
               const unsigned short* __restrict__ Bt,
               unsigned short* __restrict__ Y,
               const float* __restrict__ bias)
{
  extern __shared__ unsigned short lds[];
  constexpr int K = 2048;
  constexpr int NKT = K / 64;               // 32

  const int tid = threadIdx.x;
  const int wave = tid >> 6, lane = tid & 63;
  const int wr = wave >> 2, wc = wave & 3;
  const int l15 = lane & 15;

  // XCD-bijective 8x8 supertile swizzle
  int bid = blockIdx.x;
  int g = bid & 7, w = bid >> 3;
  int bm = (g & 1) * 8 + (w & 7);           // 0..15
  int bn = (g >> 1) * 8 + (w >> 3);         // 0..31

  const unsigned short* Ag = A  + (long)bm * 256 * K;
  const unsigned short* Bg = Bt + (long)bn * 256 * K;

  const int sr = (lane >> 3);
  const int sc = ((lane & 7) ^ sr) * 8;
  const int colx[2] = { ((0 + (lane>>4)) ^ (lane&7)) << 4,
                        ((4 + (lane>>4)) ^ (lane&7)) << 4 };

  floatx4 acc[8][4] = {};     // [mh*4+ai][nh*2+bj]
  const char* ldsc = (const char*)lds;
  short8 Aa[8], Ab[8], Ba[4], Bb[4];

#define STG_A(buf, kt, mh) do{                                                        \
    _Pragma("unroll")                                                                 \
    for(int g2=0; g2<2; ++g2){                                                        \
      gload_lds16(Ag + (long)(wr*128 + (mh)*64 + wc*16 + g2*8 + sr)*K                 \
                     + (long)(kt)*64 + sc,                                            \
                  &lds[(buf)*16384 + wr*8192 + ((mh)*64 + wc*16 + g2*8)*64 + lane*8]);\
    }                                                                                 \
  }while(0)

#define STG_B(buf, kt, nh) do{                                                        \
    _Pragma("unroll")                                                                 \
    for(int g2=0; g2<2; ++g2){                                                        \
      gload_lds16(Bg + (long)(wc*64 + (nh)*32 + wr*16 + g2*8 + sr)*K                  \
                     + (long)(kt)*64 + sc,                                            \
                  &lds[32768 + (buf)*16384 + (wc>>1)*8192                             \
                       + ((wc&1)*64 + (nh)*32 + wr*16 + g2*8)*64 + lane*8]);          \
    }                                                                                 \
  }while(0)

#define RD_A(dst, buf, mh) do{                                                        \
    const char* _b = ldsc + ((buf)*16384 + wr*8192)*2;                                \
    _Pragma("unroll")                                                                 \
    for(int ai=0; ai<4; ++ai){                                                        \
      const int _rb = ((mh)*64 + ai*16 + l15) << 7;                                   \
      dst[ai*2+0] = *(const short8*)(_b + _rb + colx[0]);                             \
      dst[ai*2+1] = *(const short8*)(_b + _rb + colx[1]);                             \
    }                                                                                 \
  }while(0)

#define RD_B(dst, buf, nh) do{                                                        \
    const char* _b = ldsc + (32768 + (buf)*16384 + (wc>>1)*8192)*2;                   \
    _Pragma("unroll")                                                                 \
    for(int bj=0; bj<2; ++bj){                                                        \
      const int _rb = ((wc&1)*64 + (nh)*32 + bj*16 + l15) << 7;                       \
      dst[bj*2+0] = *(const short8*)(_b + _rb + colx[0]);                             \
      dst[bj*2+1] = *(const short8*)(_b + _rb + colx[1]);                             \
    }                                                                                 \
  }while(0)

#define MFQ(mh, nh, As, Bs) do{                                                       \
    __builtin_amdgcn_s_setprio(1);                                                    \
    _Pragma("unroll")                                                                 \
    for(int ai=0; ai<4; ++ai)                                                         \
      _Pragma("unroll")                                                               \
      for(int bj=0; bj<2; ++bj)                                                       \
        _Pragma("unroll")                                                             \
        for(int kk=0; kk<2; ++kk)                                                     \
          acc[(mh)*4+ai][(nh)*2+bj] = __builtin_amdgcn_mfma_f32_16x16x32_bf16(        \
              As[ai*2+kk], Bs[bj*2+kk], acc[(mh)*4+ai][(nh)*2+bj], 0,0,0);            \
    __builtin_amdgcn_s_setprio(0);                                                    \
  }while(0)

#define VM4   asm volatile("s_waitcnt vmcnt(4)" ::: "memory")
#define BAR   __builtin_amdgcn_s_barrier()
#define SCHED __builtin_amdgcn_sched_barrier(0)

  STG_A(0, 0, 0); STG_B(0, 0, 0); STG_B(0, 0, 1); STG_A(0, 0, 1);
  VM4;
  BAR;
  SCHED;

  #pragma unroll 1
  for(int i=0; i<NKT/2; ++i){
    const int t1 = 2*i + 1;
    const int t2 = (2*i + 2) & (NKT - 1);

    RD_A(Aa, 0, 0); RD_B(Ba, 0, 0);
    STG_A(1, t1, 0); STG_B(1, t1, 0);
    VM4; BAR;
    MFQ(0, 0, Aa, Ba);
    BAR; SCHED;
    RD_B(Bb, 0, 1);
    STG_B(1, t1, 1);
    VM4; BAR;
    MFQ(0, 1, Aa, Bb);
    BAR; SCHED;
    RD_A(Ab, 0, 1);
    STG_A(1, t1, 1);
    VM4; BAR;
    MFQ(1, 1, Ab, Bb);
    BAR; SCHED;
    VM4; BAR;
    MFQ(1, 0, Ab, Ba);
    BAR; SCHED;

    RD_A(Aa, 1, 0); RD_B(Ba, 1, 0);
    STG_A(0, t2, 0); STG_B(0, t2, 0);
    VM4; BAR;
    MFQ(0, 0, Aa, Ba);
    BAR; SCHED;
    RD_B(Bb, 1, 1);
    STG_B(0, t2, 1);
    VM4; BAR;
    MFQ(0, 1, Aa, Bb);
    BAR; SCHED;
    RD_A(Ab, 1, 1);
    STG_A(0, t2, 1);
    VM4; BAR;
    MFQ(1, 1, Ab, Bb);
    BAR; SCHED;
    VM4; BAR;
    MFQ(1, 0, Ab, Ba);
    BAR; SCHED;
  }
#undef STG_A
#undef STG_B
#undef RD_A
#undef RD_B
#undef MFQ
#undef VM4
#undef BAR
#undef SCHED

  // epilogue: bias + section transforms, bf16 store
  #pragma unroll
  for(int mh=0;mh<2;++mh){
    #pragma unroll
    for(int ai=0;ai<4;++ai){
      const int rowi = bm*256 + wr*128 + mh*64 + ai*16 + ((lane>>4)<<2);
      #pragma unroll
      for(int nh=0;nh<2;++nh){
        #pragma unroll
        for(int bj=0;bj<2;++bj){
          const int col = bn*256 + wc*64 + nh*32 + bj*16 + l15;
          const float bs = bias[col];
          const int sec = col >> 11;
          #pragma unroll
          for(int r=0;r<4;++r){
            float v = acc[mh*4+ai][nh*2+bj][r] + bs;
            if(sec == 1) v *= KSCALE;
            else if(sec == 3) v = v / (1.f + __expf(-v));   // silu
            Y[(long)(rowi + r) * NCAT_ + col] = f2bf(v);
          }
        }
      }
    }
  }
}

// ---------------- 128^2 GEMM, flat-pipelined double-buffer (output projection) ----------------
template<int EPI>
__global__ __launch_bounds__(256)
void k_gemm(const unsigned short* __restrict__ A,
            const unsigned short* __restrict__ Bt,
            void* __restrict__ outp,
            const float* __restrict__ bias,
            int M, int Ncols, int K, int NB)
{
  __shared__ unsigned short lA[2*128*64];
  __shared__ unsigned short lB[2*128*64];
  const int bid = blockIdx.x;
  const int bm = bid / NB, bn = bid % NB;
  const int tid = threadIdx.x;
  const int wave = tid >> 6, lane = tid & 63;
  const int wr = wave >> 1, wc = wave & 1;

  floatx4 acc[4][4] = {};

  int srow[4], scol[4];
  #pragma unroll
  for(int is=0; is<4; ++is){
    int o = is*4096 + wave*1024 + lane*16;     // byte offset in 16KB tile
    int row = o >> 7;
    int logcb = (o & 127) ^ ((row & 7) << 4);  // inverse-swizzled source column
    srow[is] = row; scol[is] = logcb >> 1;
  }
  const unsigned short* Abase = A + (long)bm * 128 * K;
  const unsigned short* Bbase = Bt + (long)bn * 128 * K;

#define STG128(kt, buf) do{                                                          \
    const int _k0 = (kt) << 6;                                                       \
    _Pragma("unroll")                                                                \
    for(int is=0; is<4; ++is){                                                       \
      gload_lds16(Abase + (long)srow[is]*K + _k0 + scol[is], &lA[(buf)*8192 + ((is*4096 + wave*1024) >> 1)]); \
      gload_lds16(Bbase + (long)srow[is]*K + _k0 + scol[is], &lB[(buf)*8192 + ((is*4096 + wave*1024) >> 1)]); \
    }                                                                                \
  }while(0)

  const int nkt = K >> 6;
  STG128(0, 0);
  for(int kt=0; kt<nkt; ++kt){
    const int cur = kt & 1, nxt = cur ^ 1;
    const int ktn = (kt + 1 == nkt) ? 0 : kt + 1;
    __syncthreads();
    STG128(ktn, nxt);
    const char* cA = (const char*)lA + cur*16384;
    const char* cB = (const char*)lB + cur*16384;
    #pragma unroll
    for(int kk=0; kk<2; ++kk){
      const int cb = (kk<<6) + ((lane>>4)<<4);
      short8 af[4], bfr[4];
      #pragma unroll
      for(int i=0;i<4;++i){
        int row = (wr<<6) + (i<<4) + (lane&15);
        af[i] = *(const short8*)(cA + (row<<7) + (cb ^ ((row&7)<<4)));
      }
      #pragma unroll
      for(int j=0;j<4;++j){
        int row = (wc<<6) + (j<<4) + (lane&15);
        bfr[j] = *(const short8*)(cB + (row<<7) + (cb ^ ((row&7)<<4)));
      }
      #pragma unroll
      for(int i=0;i<4;++i)
        #pragma unroll
        for(int j=0;j<4;++j)
          acc[i][j] = __builtin_amdgcn_mfma_f32_16x16x32_bf16(af[i], bfr[j], acc[i][j], 0,0,0);
    }
  }
#undef STG128

  #pragma unroll
  for(int i=0;i<4;++i){
    #pragma unroll
    for(int j=0;j<4;++j){
      #pragma unroll
      for(int r=0;r<4;++r){
        int row = bm*128 + (wr<<6) + (i<<4) + ((lane>>4)<<2) + r;
        int col = bn*128 + (wc<<6) + (j<<4) + (lane&15);
        float v = acc[i][j][r] + bias[col];
        if(EPI == 0){
          int sec = col >> 11;
          if(sec == 1) v *= KSCALE;
          else if(sec == 3) v = v / (1.f + __expf(-v));   // silu
          ((unsigned short*)outp)[(long)row * Ncols + col] = f2bf(v);
        } else {
          ((float*)outp)[(long)row * Ncols + col] = v;
        }
      }
    }
  }
}

// ---------------- fused transpose + per-chunk summary ----------------
// Block (bh,c): loads Y's k,v half-slices, bakes decay into k, LDS-transposes,
// writes Vt (global, for k_ret), computes MS[dv][dk] = dec^127 * sum_t V[dv][t]*Ktd[dk][t]
// via MFMA from transposed LDS. Eliminates the Ktd global round-trip entirely.
__global__ __launch_bounds__(256)
void k_chunksumT(const unsigned short* __restrict__ Y,
                 unsigned short* __restrict__ Vt,
                 float* __restrict__ MS){
  __shared__ unsigned short lt[64][136];    // one op's half-slice [t_loc][d]
  __shared__ unsigned short Kt2[128][72];   // [dk][t_half] (+pad, 144B rows, 16B aligned)
  __shared__ unsigned short Vt2[128][72];   // [dv][t_half]
  int bid = blockIdx.x;                     // 512: bh*16 + c
  int bh = bid >> 4, c = bid & 15, b = bh >> 4, h = bh & 15;
  int tid = threadIdx.x, wave = tid >> 6, lane = tid & 63;
  int wr = wave >> 1, wc = wave & 1;
  float dec = 1.f - exp2f(-5.f - (float)h);
  float l2d = log2f(dec);

  floatx4 acc[4][4] = {};

  #pragma unroll 1
  for(int h2 = 0; h2 < 2; ++h2){
    // K half-slice (decay-baked) -> lt
    #pragma unroll
    for(int p=0;p<4;++p){
      int tl = p*16 + (tid>>4);             // 0..63
      int t  = h2*64 + tl;                  // 0..127 in chunk
      long row = ((long)(b*N_ + c*CH_ + t))*NCAT_ + 2048 + h*128 + (tid&15)*8;
      short8 v = *(const short8*)(Y + row);
      float f = exp2f(-(float)t * l2d);     // dec^{-t}
      #pragma unroll
      for(int u=0;u<8;++u) v[u] = (short)f2bf(bf2f((unsigned short)v[u]) * f);
      *(short8*)&lt[tl][(tid&15)*8] = v;
    }
    __syncthreads();
    // gather-transpose -> Kt2
    #pragma unroll
    for(int p=0;p<4;++p){
      int dk = p*32 + (tid>>3);
      int tc = (tid&7)*8;
      short8 o;
      #pragma unroll
      for(int u=0;u<8;++u) o[u] = (short)lt[tc+u][dk];
      *(short8*)&Kt2[dk][tc] = o;
    }
    __syncthreads();
    // V half-slice -> lt
    #pragma unroll
    for(int p=0;p<4;++p){
      int tl = p*16 + (tid>>4);
      int t  = h2*64 + tl;
      long row = ((long)(b*N_ + c*CH_ + t))*NCAT_ + 4096 + h*128 + (tid&15)*8;
      *(short8*)&lt[tl][(tid&15)*8] = *(const short8*)(Y + row);
    }
    __syncthreads();
    // gather-transpose -> Vt2 + global Vt (k_ret consumes it)
    #pragma unroll
    for(int p=0;p<4;++p){
      int dv = p*32 + (tid>>3);
      int tc = (tid&7)*8;
      short8 o;
      #pragma unroll
      for(int u=0;u<8;++u) o[u] = (short)lt[tc+u][dv];
      *(short8*)&Vt2[dv][tc] = o;
      *(short8*)(Vt + ((long)(bh*128 + dv))*N_ + c*CH_ + h2*64 + tc) = o;
    }
    __syncthreads();
    // MFMA over this half's t (2 ksteps of 32), accumulate across halves
    #pragma unroll
    for(int kk=0;kk<2;++kk){
      int tl = kk*32 + ((lane>>4)<<3);
      short8 af[4], bfr[4];
      #pragma unroll
      for(int i=0;i<4;++i){ int dv = (wr<<6)+(i<<4)+(lane&15); af[i]  = *(const short8*)&Vt2[dv][tl]; }
      #pragma unroll
      for(int j=0;j<4;++j){ int dk = (wc<<6)+(j<<4)+(lane&15); bfr[j] = *(const short8*)&Kt2[dk][tl]; }
      #pragma unroll
      for(int i=0;i<4;++i)
        #pragma unroll
        for(int j=0;j<4;++j)
          acc[i][j] = __builtin_amdgcn_mfma_f32_16x16x32_bf16(af[i], bfr[j], acc[i][j], 0,0,0);
    }
    __syncthreads();   // Kt2/Vt2 reads done before next half overwrites
  }

  float scale = exp2f(127.f * log2f(dec));    // dec^{C-1}
  float* Mo = MS + ((long)bh*NC_ + c) * 16384;
  #pragma unroll
  for(int i=0;i<4;++i)
    #pragma unroll
    for(int j=0;j<4;++j)
      #pragma unroll
      for(int r=0;r<4;++r){
        int dv = (wr<<6)+(i<<4)+((lane>>4)<<2)+r;
        int dk = (wc<<6)+(j<<4)+(lane&15);
        Mo[dv*128 + dk] = acc[i][j][r] * scale;
      }
}

// ---------------- parallel scan over chunks (elementwise over state entries) ----------------
__global__ __launch_bounds__(256)
void k_scan(const float* __restrict__ MS, unsigned short* __restrict__ Scb,
            float* __restrict__ stateOut){
  int bid = blockIdx.x;
  int bh = bid >> 4, p = bid & 15;
  int tid = threadIdx.x, h = bh & 15;
  float dec = 1.f - exp2f(-5.f - (float)h);
  float decC = exp2f(128.f * log2f(dec));     // dec^C
  int e0 = p*1024 + tid*4;
  floatx4 S = {0.f, 0.f, 0.f, 0.f};
  const float* base = MS + (long)bh * NC_ * 16384 + e0;
  unsigned short* sb = Scb + (long)bh * NC_ * 16384 + e0;
  for(int c=0;c<NC_;++c){
    floatx4 m = *(const floatx4*)(base + (long)c*16384);
    short4v q;
    #pragma unroll
    for(int u=0;u<4;++u) q[u] = (short)f2bf(S[u]);
    *(short4v*)(sb + (long)c*16384) = q;
    S = decC * S + m;
  }
  // final state: element e = dv*128+dk (transposed layout) -> out [b][h][dk][dv]
  int dv = e0 >> 7, dk = e0 & 127;
  float* so = stateOut + (long)bh*16384 + dv;
  #pragma unroll
  for(int u=0;u<4;++u) so[(long)(dk+u)*128] = S[u];
}

// ---------------- retention output: masked decayed QK^T @ V + cross, group-norm, gate ----------------
__global__ __launch_bounds__(256)
void k_ret(const unsigned short* __restrict__ Y, const unsigned short* __restrict__ Vt,
           const unsigned short* __restrict__ Scb, unsigned short* __restrict__ RG){
  __shared__ unsigned short sQ[128*128];   // Qd = q * dec^t   (swizzled)
  __shared__ unsigned short sK[128*128];   // Kd = k * dec^-s ; reused for P
  int bid = blockIdx.x;
  int bh = bid >> 4, c = bid & 15, b = bh >> 4, h = bh & 15;
  int tid = threadIdx.x, w = tid >> 6, lane = tid & 63;
  float dec = 1.f - exp2f(-5.f - (float)h);
  float l2d = log2f(dec);

  #pragma unroll
  for(int p=0;p<8;++p){
    int t = p*16 + (tid>>4);
    long row = (long)(b*N_ + c*CH_ + t) * NCAT_ + h*128 + (tid&15)*8;
    short8 qv = *(const short8*)(Y + row);          // q section
    short8 kv = *(const short8*)(Y + row + 2048);   // k section
    float fq = exp2f((float)t * l2d);
    float fk = exp2f(-(float)t * l2d);
    short8 qs, ks;
    #pragma unroll
    for(int u=0;u<8;++u){
      qs[u] = (short)f2bf(bf2f((unsigned short)qv[u]) * fq);
      ks[u] = (short)f2bf(bf2f((unsigned short)kv[u]) * fk);
    }
    int ad = t*256 + (((tid&15)*16) ^ ((t&7)<<4));
    *(short8*)((char*)sQ + ad) = qs;
    *(short8*)((char*)sK + ad) = ks;
  }
  __syncthreads();

  floatx4 acc[2][8] = {};
  // QK^T (already includes dec^{t-s})
  #pragma unroll
  for(int kk=0;kk<4;++kk){
    int cb = (kk<<6) + ((lane>>4)<<4);
    short8 af[2], bfr[8];
    #pragma unroll
    for(int i=0;i<2;++i){ int t = w*32 + (i<<4) + (lane&15); af[i] = *(const short8*)((const char*)sQ + t*256 + (cb ^ ((t&7)<<4))); }
    #pragma unroll
    for(int j=0;j<8;++j){ int s = (j<<4) + (lane&15); bfr[j] = *(const short8*)((const char*)sK + s*256 + (cb ^ ((s&7)<<4))); }
    #pragma unroll
    for(int i=0;i<2;++i)
      #pragma unroll
      for(int j=0;j<8;++j)
        acc[i][j] = __builtin_amdgcn_mfma_f32_16x16x32_bf16(af[i], bfr[j], acc[i][j], 0,0,0);
  }
  __syncthreads();   // all waves done reading sK

  // causal mask, write P (bf16) into sK
  #pragma unroll
  for(int i=0;i<2;++i)
    #pragma unroll
    for(int j=0;j<8;++j)
      #pragma unroll
      for(int r=0;r<4;++r){
        int t = w*32 + (i<<4) + ((lane>>4)<<2) + r;
        int s = (j<<4) + (lane&15);
        float v = (s <= t) ? acc[i][j][r] : 0.f;
        *(unsigned short*)((char*)sK + t*256 + ((s*2) ^ ((t&7)<<4))) = f2bf(v);
      }
  __syncthreads();

  #pragma unroll
  for(int i=0;i<2;++i)
    #pragma unroll
    for(int j=0;j<8;++j)
      #pragma unroll
      for(int u=0;u<4;++u) acc[i][j][u] = 0.f;

  // ret = P @ V
  const unsigned short* Vb = Vt + (long)bh*128*N_ + c*CH_;
  #pragma unroll
  for(int kk=0;kk<4;++kk){
    int cb = (kk<<6) + ((lane>>4)<<4);
    int sg = kk*32 + ((lane>>4)<<3);
    short8 af[2], bfr[8];
    #pragma unroll
    for(int i=0;i<2;++i){ int t = w*32 + (i<<4) + (lane&15); af[i] = *(const short8*)((const char*)sK + t*256 + (cb ^ ((t&7)<<4))); }
    #pragma unroll
    for(int j=0;j<8;++j){ int dv = (j<<4) + (lane&15); bfr[j] = *(const short8*)(Vb + (long)dv*N_ + sg); }
    #pragma unroll
    for(int i=0;i<2;++i)
      #pragma unroll
      for(int j=0;j<8;++j)
        acc[i][j] = __builtin_amdgcn_mfma_f32_16x16x32_bf16(af[i], bfr[j], acc[i][j], 0,0,0);
  }
  // + dec^{t+1} * q @ S_c   (A = Qd*dec, B = Scb[dv][dk])
  const unsigned short* Sb = Scb + ((long)bh*NC_ + c) * 16384;
  #pragma unroll
  for(int kk=0;kk<4;++kk){
    int cb = (kk<<6) + ((lane>>4)<<4);
    int kg = kk*32 + ((lane>>4)<<3);
    short8 af[2], bfr[8];
    #pragma unroll
    for(int i=0;i<2;++i){
      int t = w*32 + (i<<4) + (lane&15);
      short8 qv = *(const short8*)((const char*)sQ + t*256 + (cb ^ ((t&7)<<4)));
      #pragma unroll
      for(int u=0;u<8;++u) af[i][u] = (short)f2bf(bf2f((unsigned short)qv[u]) * dec);
    }
    #pragma unroll
    for(int j=0;j<8;++j){ int dv = (j<<4) + (lane&15); bfr[j] = *(const short8*)(Sb + (long)dv*128 + kg); }
    #pragma unroll
    for(int i=0;i<2;++i)
      #pragma unroll
      for(int j=0;j<8;++j)
        acc[i][j] = __builtin_amdgcn_mfma_f32_16x16x32_bf16(af[i], bfr[j], acc[i][j], 0,0,0);
  }

  // group-norm over DV per row, gate, write bf16
  #pragma unroll
  for(int i=0;i<2;++i){
    #pragma unroll
    for(int r=0;r<4;++r){
      float s1 = 0.f, s2 = 0.f;
      #pragma unroll
      for(int j=0;j<8;++j){ float v = acc[i][j][r]; s1 += v; s2 += v*v; }
      #pragma unroll
      for(int off=1; off<16; off<<=1){ s1 += __shfl_xor(s1, off); s2 += __shfl_xor(s2, off); }
      float mu  = s1 * (1.f/128.f);
      float var = s2 * (1.f/128.f) - mu*mu;
      float inv = rsqrtf(var + 1e-6f);
      int t = w*32 + (i<<4) + ((lane>>4)<<2) + r;
      long mrow = (long)(b*N_ + c*CH_ + t);
      #pragma unroll
      for(int j=0;j<8;++j){
        int dv = (j<<4) + (lane&15);
        float v = (acc[i][j][r] - mu) * inv;
        float g = bf2f(Y[mrow*NCAT_ + 6144 + h*128 + dv]);
        RG[mrow*E_ + h*128 + dv] = f2bf(v * g);
      }
    }
  }
}

// ---------------- launch ----------------
extern "C" void kernel_launch(void* const* d_in, const int* in_sizes, int n_in,
                              void* d_out, int out_size, void* d_ws, size_t ws_size,
                              hipStream_t stream) {
  const float* x  = (const float*)d_in[0];
  const float* Wq = (const float*)d_in[1];
  const float* bq = (const float*)d_in[2];
  const float* Wk = (const float*)d_in[3];
  const float* bk = (const float*)d_in[4];
  const float* Wv = (const float*)d_in[5];
  const float* bv = (const float*)d_in[6];
  const float* Wg = (const float*)d_in[7];
  const float* bg = (const float*)d_in[8];
  const float* Wo = (const float*)d_in[9];
  const float* bo = (const float*)d_in[10];

  char* ws = (char*)d_ws;
  unsigned short* xb   = (unsigned short*)(ws + OFF_XB);
  unsigned short* Wcat = (unsigned short*)(ws + OFF_WCAT);
  unsigned short* Wob  = (unsigned short*)(ws + OFF_WOB);
  float*          bcat = (float*)(ws + OFF_BCAT);
  unsigned short* Y    = (unsigned short*)(ws + OFF_Y);
  unsigned short* Vt   = (unsigned short*)(ws + OFF_VT);
  unsigned short* Scb  = (unsigned short*)(ws + OFF_SCB);
  float*          MS   = (float*)(ws + OFF_WCAT);   // reuse after GEMM1
  unsigned short* RG   = (unsigned short*)(ws + OFF_XB); // reuse after GEMM1

  float* outp     = (float*)d_out;
  float* stateOut = outp + (long)M_ * E_;   // 8,388,608

  // allow 128KB dynamic LDS for the 256^2 GEMM
  (void)hipFuncSetAttribute((const void*)k_gemm256,
                            hipFuncAttributeMaxDynamicSharedMemorySize, 131072);

  // fused prep (all casts + bias concat)
  k_castall<<<14340, 256, 0, stream>>>(x, Wq, Wk, Wv, Wg, Wo, bq, bk, bv, bg,
                                       xb, Wcat, Wob, bcat);

  // fused QKVG projection (256^2, 8-phase)
  k_gemm256<<<512, 512, 131072, stream>>>(xb, Wcat, Y, bcat);

  // fused transpose + per-chunk summary (writes Vt + MS)
  k_chunksumT<<<512, 256, 0, stream>>>(Y, Vt, MS);

  // sequential-over-chunks scan (parallel over state elements)
  k_scan<<<512, 256, 0, stream>>>(MS, Scb, stateOut);

  // retention output (masked QK^T @ V + cross term, group-norm, gate)
  k_ret<<<512, 256, 0, stream>>>(Y, Vt, Scb, RG);

  // output projection
  k_gemm<1><<<(M_/128)*(E_/128), 256, 0, stream>>>(RG, Wob, (void*)outp, bo, M_, E_, E_, E_/128);
}

// Round 10
// 252.711 us; speedup vs baseline: 1.4252x; 1.0340x over previous
//
#include <hip/hip_runtime.h>
#include <hip/hip_bf16.h>

typedef __attribute__((ext_vector_type(8))) short short8;
typedef __attribute__((ext_vector_type(4))) short short4v;
typedef __attribute__((ext_vector_type(4))) float floatx4;

#define DI __device__ __forceinline__

// Problem constants
constexpr int B_ = 2, N_ = 2048, H_ = 16, DK_ = 128, DV_ = 128, E_ = 2048;
constexpr int M_ = B_ * N_;          // 4096 token rows
constexpr int NCAT_ = 4 * E_;        // 8192 = q|k|v|g concat
constexpr int CH_ = 128;             // chunk length
constexpr int NC_ = N_ / CH_;        // 16 chunks
constexpr float KSCALE = 0.08838834764831845f; // 1/sqrt(128)

// Workspace layout (bytes)
constexpr long OFF_XB   = 0;                    // 16MB  bf16 x      (reused as RG after GEMM1)
constexpr long OFF_WCAT = 16777216;             // 32MB  bf16 Wq|Wk|Wv|Wg  (reused as MS bf16 after GEMM1)
constexpr long OFF_WOB  = 50331648;             // 8MB   bf16 Wo
constexpr long OFF_BCAT = 58720256;             // 32KB  f32 concat bias
constexpr long OFF_Y    = 58753024;             // 64MB  bf16 [4096][8192] q|k|v|silu(g)
constexpr long OFF_VT   = 142639104;            // 16MB  bf16 Vt  [b][h][dv][t]
constexpr long OFF_SCB  = 159416320;            // 16MB  bf16 per-chunk start states [bh][c][dv][dk]

DI unsigned short f2bf(float f){
  unsigned u = __float_as_uint(f);
  u += 0x7fffu + ((u >> 16) & 1u);
  return (unsigned short)(u >> 16);
}
DI float bf2f(unsigned short s){ return __uint_as_float(((unsigned)s) << 16); }

DI void gload_lds16(const void* g, void* l){
  __builtin_amdgcn_global_load_lds(
      (const __attribute__((address_space(1))) unsigned int*)g,
      (__attribute__((address_space(3))) unsigned int*)l, 16, 0, 0);
}

// ---------------- fused prep: all f32->bf16 casts + bias concat ----------------
__global__ void k_castall(const float* __restrict__ x,
                          const float* __restrict__ Wq, const float* __restrict__ Wk,
                          const float* __restrict__ Wv, const float* __restrict__ Wg,
                          const float* __restrict__ Wo,
                          const float* __restrict__ bq, const float* __restrict__ bk,
                          const float* __restrict__ bv, const float* __restrict__ bg,
                          unsigned short* __restrict__ xb, unsigned short* __restrict__ Wcat,
                          unsigned short* __restrict__ Wob, float* __restrict__ bcat){
  int bid = blockIdx.x;
  if(bid >= 14336){
    int i = (bid - 14336) * 2048 + threadIdx.x * 8;
    #pragma unroll
    for(int u=0;u<8;++u){
      int j = i + u;
      float v;
      if(j < 2048)      v = bq[j];
      else if(j < 4096) v = bk[j - 2048];
      else if(j < 6144) v = bv[j - 4096];
      else              v = bg[j - 6144];
      bcat[j] = v;
    }
    return;
  }
  const float* s; unsigned short* d; long off;
  if(bid < 4096){ s = x; d = xb; off = (long)bid*2048; }
  else if(bid < 6144){ s = Wq; d = Wcat;            off = (long)(bid-4096)*2048; }
  else if(bid < 8192){ s = Wk; d = Wcat + 4194304L; off = (long)(bid-6144)*2048; }
  else if(bid < 10240){ s = Wv; d = Wcat + 8388608L; off = (long)(bid-8192)*2048; }
  else if(bid < 12288){ s = Wg; d = Wcat + 12582912L; off = (long)(bid-10240)*2048; }
  else { s = Wo; d = Wob; off = (long)(bid-12288)*2048; }
  long i = off + (long)threadIdx.x * 8;
  float4 v0 = *(const float4*)(s + i);
  float4 v1 = *(const float4*)(s + i + 4);
  short8 o;
  o[0]=(short)f2bf(v0.x); o[1]=(short)f2bf(v0.y); o[2]=(short)f2bf(v0.z); o[3]=(short)f2bf(v0.w);
  o[4]=(short)f2bf(v1.x); o[5]=(short)f2bf(v1.y); o[6]=(short)f2bf(v1.z); o[7]=(short)f2bf(v1.w);
  *(short8*)(d + i) = o;
}

// ================= 256x256 GEMM, 8-phase schedule (R8, banked) =================
__global__ __launch_bounds__(512, 2)
void k_gemm256(const unsigned short* __restrict__ A,
               const unsigned short* __restrict__ Bt,
               unsigned short* __restrict__ Y,
               const float* __restrict__ bias)
{
  extern __shared__ unsigned short lds[];
  constexpr int K = 2048;
  constexpr int NKT = K / 64;               // 32

  const int tid = threadIdx.x;
  const int wave = tid >> 6, lane = tid & 63;
  const int wr = wave >> 2, wc = wave & 3;
  const int l15 = lane & 15;

  int bid = blockIdx.x;
  int g = bid & 7, w = bid >> 3;
  int bm = (g & 1) * 8 + (w & 7);           // 0..15
  int bn = (g >> 1) * 8 + (w >> 3);         // 0..31

  const unsigned short* Ag = A  + (long)bm * 256 * K;
  const unsigned short* Bg = Bt + (long)bn * 256 * K;

  const int sr = (lane >> 3);
  const int sc = ((lane & 7) ^ sr) * 8;
  const int colx[2] = { ((0 + (lane>>4)) ^ (lane&7)) << 4,
                        ((4 + (lane>>4)) ^ (lane&7)) << 4 };

  floatx4 acc[8][4] = {};     // [mh*4+ai][nh*2+bj]
  const char* ldsc = (const char*)lds;
  short8 Aa[8], Ab[8], Ba[4], Bb[4];

#define STG_A(buf, kt, mh) do{                                                        \
    _Pragma("unroll")                                                                 \
    for(int g2=0; g2<2; ++g2){                                                        \
      gload_lds16(Ag + (long)(wr*128 + (mh)*64 + wc*16 + g2*8 + sr)*K                 \
                     + (long)(kt)*64 + sc,                                            \
                  &lds[(buf)*16384 + wr*8192 + ((mh)*64 + wc*16 + g2*8)*64 + lane*8]);\
    }                                                                                 \
  }while(0)

#define STG_B(buf, kt, nh) do{                                                        \
    _Pragma("unroll")                                                                 \
    for(int g2=0; g2<2; ++g2){                                                        \
      gload_lds16(Bg + (long)(wc*64 + (nh)*32 + wr*16 + g2*8 + sr)*K                  \
                     + (long)(kt)*64 + sc,                                            \
                  &lds[32768 + (buf)*16384 + (wc>>1)*8192                             \
                       + ((wc&1)*64 + (nh)*32 + wr*16 + g2*8)*64 + lane*8]);          \
    }                                                                                 \
  }while(0)

#define RD_A(dst, buf, mh) do{                                                        \
    const char* _b = ldsc + ((buf)*16384 + wr*8192)*2;                                \
    _Pragma("unroll")                                                                 \
    for(int ai=0; ai<4; ++ai){                                                        \
      const int _rb = ((mh)*64 + ai*16 + l15) << 7;                                   \
      dst[ai*2+0] = *(const short8*)(_b + _rb + colx[0]);                             \
      dst[ai*2+1] = *(const short8*)(_b + _rb + colx[1]);                             \
    }                                                                                 \
  }while(0)

#define RD_B(dst, buf, nh) do{                                                        \
    const char* _b = ldsc + (32768 + (buf)*16384 + (wc>>1)*8192)*2;                   \
    _Pragma("unroll")                                                                 \
    for(int bj=0; bj<2; ++bj){                                                        \
      const int _rb = ((wc&1)*64 + (nh)*32 + bj*16 + l15) << 7;                       \
      dst[bj*2+0] = *(const short8*)(_b + _rb + colx[0]);                             \
      dst[bj*2+1] = *(const short8*)(_b + _rb + colx[1]);                             \
    }                                                                                 \
  }while(0)

#define MFQ(mh, nh, As, Bs) do{                                                       \
    __builtin_amdgcn_s_setprio(1);                                                    \
    _Pragma("unroll")                                                                 \
    for(int ai=0; ai<4; ++ai)                                                         \
      _Pragma("unroll")                                                               \
      for(int bj=0; bj<2; ++bj)                                                       \
        _Pragma("unroll")                                                             \
        for(int kk=0; kk<2; ++kk)                                                     \
          acc[(mh)*4+ai][(nh)*2+bj] = __builtin_amdgcn_mfma_f32_16x16x32_bf16(        \
              As[ai*2+kk], Bs[bj*2+kk], acc[(mh)*4+ai][(nh)*2+bj], 0,0,0);            \
    __builtin_amdgcn_s_setprio(0);                                                    \
  }while(0)

#define VM4   asm volatile("s_waitcnt vmcnt(4)" ::: "memory")
#define BAR   __builtin_amdgcn_s_barrier()
#define SCHED __builtin_amdgcn_sched_barrier(0)

  STG_A(0, 0, 0); STG_B(0, 0, 0); STG_B(0, 0, 1); STG_A(0, 0, 1);
  VM4;
  BAR;
  SCHED;

  #pragma unroll 1
  for(int i=0; i<NKT/2; ++i){
    const int t1 = 2*i + 1;
    const int t2 = (2*i + 2) & (NKT - 1);

    RD_A(Aa, 0, 0); RD_B(Ba, 0, 0);
    STG_A(1, t1, 0); STG_B(1, t1, 0);
    VM4; BAR;
    MFQ(0, 0, Aa, Ba);
    BAR; SCHED;
    RD_B(Bb, 0, 1);
    STG_B(1, t1, 1);
    VM4; BAR;
    MFQ(0, 1, Aa, Bb);
    BAR; SCHED;
    RD_A(Ab, 0, 1);
    STG_A(1, t1, 1);
    VM4; BAR;
    MFQ(1, 1, Ab, Bb);
    BAR; SCHED;
    VM4; BAR;
    MFQ(1, 0, Ab, Ba);
    BAR; SCHED;

    RD_A(Aa, 1, 0); RD_B(Ba, 1, 0);
    STG_A(0, t2, 0); STG_B(0, t2, 0);
    VM4; BAR;
    MFQ(0, 0, Aa, Ba);
    BAR; SCHED;
    RD_B(Bb, 1, 1);
    STG_B(0, t2, 1);
    VM4; BAR;
    MFQ(0, 1, Aa, Bb);
    BAR; SCHED;
    RD_A(Ab, 1, 1);
    STG_A(0, t2, 1);
    VM4; BAR;
    MFQ(1, 1, Ab, Bb);
    BAR; SCHED;
    VM4; BAR;
    MFQ(1, 0, Ab, Ba);
    BAR; SCHED;
  }
#undef STG_A
#undef STG_B
#undef RD_A
#undef RD_B
#undef MFQ
#undef VM4
#undef BAR
#undef SCHED

  // epilogue: bias + section transforms, bf16 store
  #pragma unroll
  for(int mh=0;mh<2;++mh){
    #pragma unroll
    for(int ai=0;ai<4;++ai){
      const int rowi = bm*256 + wr*128 + mh*64 + ai*16 + ((lane>>4)<<2);
      #pragma unroll
      for(int nh=0;nh<2;++nh){
        #pragma unroll
        for(int bj=0;bj<2;++bj){
          const int col = bn*256 + wc*64 + nh*32 + bj*16 + l15;
          const float bs = bias[col];
          const int sec = col >> 11;
          #pragma unroll
          for(int r=0;r<4;++r){
            float v = acc[mh*4+ai][nh*2+bj][r] + bs;
            if(sec == 1) v *= KSCALE;
            else if(sec == 3) v = v / (1.f + __expf(-v));   // silu
            Y[(long)(rowi + r) * NCAT_ + col] = f2bf(v);
          }
        }
      }
    }
  }
}

// ================= 256x128 GEMM (output projection), 4-phase counted-vmcnt =================
// 512 thr = 8 waves (4M x 2N), wave tile 64x64, acc[4][4]=64 AGPR. BK=64.
// LDS 96KB: A [buf][256][64] 32KB x2, B [buf][128][64] 16KB x2 at byte 65536.
// A band 2-way shared, B band 4-way -> per-tile LDS demand ~176KB (~1375cy) vs
// GEMM1's 256KB. Per-wave-owned staging bands; uniform vmcnt(6) (= 1 stage set);
// stage (buf1,u+1) at p1 (buf1 last read prev p4, BAR-protected), (buf0,u+2) at p3.
__global__ __launch_bounds__(512, 2)
void k_gemm2(const unsigned short* __restrict__ A,
             const unsigned short* __restrict__ Bt,
             float* __restrict__ outp,
             const float* __restrict__ bias)
{
  extern __shared__ unsigned short lds[];
  constexpr int K = 2048;
  constexpr int NKT = K / 64;               // 32

  const int tid = threadIdx.x;
  const int wave = tid >> 6, lane = tid & 63;
  const int wm = wave >> 1, wn = wave & 1;
  const int l15 = lane & 15;

  int bid = blockIdx.x;
  int g = bid & 7, w = bid >> 3;            // w 0..31
  int bm = (g & 1) * 8 + (w & 7);           // 0..15
  int bn = (g >> 1) * 4 + (w >> 3);         // 0..15

  const unsigned short* Ag = A  + (long)bm * 256 * K;
  const unsigned short* Bg = Bt + (long)bn * 128 * K;

  const int sr = lane >> 3;
  const int sc = ((lane & 7) ^ sr) * 8;
  const int colx[2] = { (((lane>>4)  ) ^ (lane&7)) << 4,
                        (((lane>>4)+4) ^ (lane&7)) << 4 };

  floatx4 acc[4][4] = {};
  const char* ldsc = (const char*)lds;
  short8 Av[8], Bv[4], Bw[4];

#define STG_AB(buf, kt) do{                                                           \
    _Pragma("unroll")                                                                 \
    for(int g2=0; g2<4; ++g2){                                                        \
      gload_lds16(Ag + (long)(wm*64 + wn*32 + g2*8 + sr)*K + (long)(kt)*64 + sc,      \
                  &lds[(buf)*16384 + (wm*64 + wn*32 + g2*8)*64 + lane*8]);            \
    }                                                                                 \
    _Pragma("unroll")                                                                 \
    for(int g2=0; g2<2; ++g2){                                                        \
      gload_lds16(Bg + (long)(wn*64 + wm*16 + g2*8 + sr)*K + (long)(kt)*64 + sc,      \
                  &lds[32768 + (buf)*8192 + (wn*64 + wm*16 + g2*8)*64 + lane*8]);     \
    }                                                                                 \
  }while(0)

#define RD_A2(buf) do{                                                                \
    const char* _b = ldsc + (buf)*32768;                                              \
    _Pragma("unroll")                                                                 \
    for(int ai=0; ai<4; ++ai){                                                        \
      const int _rb = (wm*64 + ai*16 + l15) << 7;                                     \
      Av[ai*2+0] = *(const short8*)(_b + _rb + colx[0]);                              \
      Av[ai*2+1] = *(const short8*)(_b + _rb + colx[1]);                              \
    }                                                                                 \
  }while(0)

#define RD_B2(dst, buf, half) do{                                                     \
    const char* _b = ldsc + 65536 + (buf)*16384;                                      \
    _Pragma("unroll")                                                                 \
    for(int bj=0; bj<2; ++bj){                                                        \
      const int _rb = (wn*64 + ((half)*2+bj)*16 + l15) << 7;                          \
      dst[bj*2+0] = *(const short8*)(_b + _rb + colx[0]);                             \
      dst[bj*2+1] = *(const short8*)(_b + _rb + colx[1]);                             \
    }                                                                                 \
  }while(0)

#define MF8(half, Bs) do{                                                             \
    __builtin_amdgcn_s_setprio(1);                                                    \
    _Pragma("unroll")                                                                 \
    for(int ai=0; ai<4; ++ai)                                                         \
      _Pragma("unroll")                                                               \
      for(int bj=0; bj<2; ++bj)                                                       \
        _Pragma("unroll")                                                             \
        for(int kk=0; kk<2; ++kk)                                                     \
          acc[ai][(half)*2+bj] = __builtin_amdgcn_mfma_f32_16x16x32_bf16(             \
              Av[ai*2+kk], Bs[bj*2+kk], acc[ai][(half)*2+bj], 0,0,0);                 \
    __builtin_amdgcn_s_setprio(0);                                                    \
  }while(0)

#define VM6   asm volatile("s_waitcnt vmcnt(6)" ::: "memory")
#define BAR   __builtin_amdgcn_s_barrier()
#define SCHED __builtin_amdgcn_sched_barrier(0)

  STG_AB(0, 0);   // prologue: tile0 -> buf0 (6 loads in flight)

  #pragma unroll 1
  for(int i=0; i<NKT/2; ++i){
    const int u = 2*i;
    // p1: stage (buf1, u+1); wait (buf0, u); compute buf0 x B-half0
    STG_AB(1, u+1);
    VM6; BAR;
    RD_A2(0); RD_B2(Bv, 0, 0);
    MF8(0, Bv);
    SCHED;
    // p2: compute buf0 x B-half1; end-BAR frees buf0 for restage
    RD_B2(Bw, 0, 1);
    MF8(1, Bw);
    BAR; SCHED;
    // p3: stage (buf0, u+2); wait (buf1, u+1); compute buf1 x B-half0
    STG_AB(0, (u+2) & (NKT-1));
    VM6; BAR;
    RD_A2(1); RD_B2(Bv, 1, 0);
    MF8(0, Bv);
    SCHED;
    // p4: compute buf1 x B-half1; end-BAR frees buf1
    RD_B2(Bw, 1, 1);
    MF8(1, Bw);
    BAR; SCHED;
  }
#undef STG_AB
#undef RD_A2
#undef RD_B2
#undef MF8
#undef VM6
#undef BAR
#undef SCHED

  // epilogue: f32 out + bias
  #pragma unroll
  for(int ai=0;ai<4;++ai){
    const int row = bm*256 + wm*64 + ai*16 + ((lane>>4)<<2);
    #pragma unroll
    for(int bj=0;bj<4;++bj){
      const int col = bn*128 + wn*64 + bj*16 + l15;
      const float bs = bias[col];
      #pragma unroll
      for(int r=0;r<4;++r)
        outp[(long)(row + r)*E_ + col] = acc[ai][bj][r] + bs;
    }
  }
}

// ---------------- fused transpose + per-chunk summary (MS now bf16) ----------------
__global__ __launch_bounds__(256)
void k_chunksumT(const unsigned short* __restrict__ Y,
                 unsigned short* __restrict__ Vt,
                 unsigned short* __restrict__ MS){
  __shared__ unsigned short lt[64][136];    // one op's half-slice [t_loc][d]
  __shared__ unsigned short Kt2[128][72];   // [dk][t_half]
  __shared__ unsigned short Vt2[128][72];   // [dv][t_half]
  int bid = blockIdx.x;                     // 512: bh*16 + c
  int bh = bid >> 4, c = bid & 15, b = bh >> 4, h = bh & 15;
  int tid = threadIdx.x, wave = tid >> 6, lane = tid & 63;
  int wr = wave >> 1, wc = wave & 1;
  float dec = 1.f - exp2f(-5.f - (float)h);
  float l2d = log2f(dec);

  floatx4 acc[4][4] = {};

  #pragma unroll 1
  for(int h2 = 0; h2 < 2; ++h2){
    #pragma unroll
    for(int p=0;p<4;++p){
      int tl = p*16 + (tid>>4);
      int t  = h2*64 + tl;
      long row = ((long)(b*N_ + c*CH_ + t))*NCAT_ + 2048 + h*128 + (tid&15)*8;
      short8 v = *(const short8*)(Y + row);
      float f = exp2f(-(float)t * l2d);
      #pragma unroll
      for(int u=0;u<8;++u) v[u] = (short)f2bf(bf2f((unsigned short)v[u]) * f);
      *(short8*)&lt[tl][(tid&15)*8] = v;
    }
    __syncthreads();
    #pragma unroll
    for(int p=0;p<4;++p){
      int dk = p*32 + (tid>>3);
      int tc = (tid&7)*8;
      short8 o;
      #pragma unroll
      for(int u=0;u<8;++u) o[u] = (short)lt[tc+u][dk];
      *(short8*)&Kt2[dk][tc] = o;
    }
    __syncthreads();
    #pragma unroll
    for(int p=0;p<4;++p){
      int tl = p*16 + (tid>>4);
      int t  = h2*64 + tl;
      long row = ((long)(b*N_ + c*CH_ + t))*NCAT_ + 4096 + h*128 + (tid&15)*8;
      *(short8*)&lt[tl][(tid&15)*8] = *(const short8*)(Y + row);
    }
    __syncthreads();
    #pragma unroll
    for(int p=0;p<4;++p){
      int dv = p*32 + (tid>>3);
      int tc = (tid&7)*8;
      short8 o;
      #pragma unroll
      for(int u=0;u<8;++u) o[u] = (short)lt[tc+u][dv];
      *(short8*)&Vt2[dv][tc] = o;
      *(short8*)(Vt + ((long)(bh*128 + dv))*N_ + c*CH_ + h2*64 + tc) = o;
    }
    __syncthreads();
    #pragma unroll
    for(int kk=0;kk<2;++kk){
      int tl = kk*32 + ((lane>>4)<<3);
      short8 af[4], bfr[4];
      #pragma unroll
      for(int i=0;i<4;++i){ int dv = (wr<<6)+(i<<4)+(lane&15); af[i]  = *(const short8*)&Vt2[dv][tl]; }
      #pragma unroll
      for(int j=0;j<4;++j){ int dk = (wc<<6)+(j<<4)+(lane&15); bfr[j] = *(const short8*)&Kt2[dk][tl]; }
      #pragma unroll
      for(int i=0;i<4;++i)
        #pragma unroll
        for(int j=0;j<4;++j)
          acc[i][j] = __builtin_amdgcn_mfma_f32_16x16x32_bf16(af[i], bfr[j], acc[i][j], 0,0,0);
    }
    __syncthreads();
  }

  float scale = exp2f(127.f * log2f(dec));    // dec^{C-1}
  unsigned short* Mo = MS + ((long)bh*NC_ + c) * 16384;
  #pragma unroll
  for(int i=0;i<4;++i)
    #pragma unroll
    for(int j=0;j<4;++j)
      #pragma unroll
      for(int r=0;r<4;++r){
        int dv = (wr<<6)+(i<<4)+((lane>>4)<<2)+r;
        int dk = (wc<<6)+(j<<4)+(lane&15);
        Mo[dv*128 + dk] = f2bf(acc[i][j][r] * scale);
      }
}

// ---------------- parallel scan over chunks (MS bf16 in) ----------------
__global__ __launch_bounds__(256)
void k_scan(const unsigned short* __restrict__ MS, unsigned short* __restrict__ Scb,
            float* __restrict__ stateOut){
  int bid = blockIdx.x;
  int bh = bid >> 4, p = bid & 15;
  int tid = threadIdx.x, h = bh & 15;
  float dec = 1.f - exp2f(-5.f - (float)h);
  float decC = exp2f(128.f * log2f(dec));     // dec^C
  int e0 = p*1024 + tid*4;
  floatx4 S = {0.f, 0.f, 0.f, 0.f};
  const unsigned short* base = MS + (long)bh * NC_ * 16384 + e0;
  unsigned short* sb = Scb + (long)bh * NC_ * 16384 + e0;
  for(int c=0;c<NC_;++c){
    short4v m = *(const short4v*)(base + (long)c*16384);
    short4v q;
    #pragma unroll
    for(int u=0;u<4;++u) q[u] = (short)f2bf(S[u]);
    *(short4v*)(sb + (long)c*16384) = q;
    #pragma unroll
    for(int u=0;u<4;++u) S[u] = decC * S[u] + bf2f((unsigned short)m[u]);
  }
  // final state: element e = dv*128+dk (transposed layout) -> out [b][h][dk][dv]
  int dv = e0 >> 7, dk = e0 & 127;
  float* so = stateOut + (long)bh*16384 + dv;
  #pragma unroll
  for(int u=0;u<4;++u) so[(long)(dk+u)*128] = S[u];
}

// ---------------- retention output: masked decayed QK^T @ V + cross, group-norm, gate ----------------
__global__ __launch_bounds__(256)
void k_ret(const unsigned short* __restrict__ Y, const unsigned short* __restrict__ Vt,
           const unsigned short* __restrict__ Scb, unsigned short* __restrict__ RG){
  __shared__ unsigned short sQ[128*128];   // Qd = q * dec^t   (swizzled)
  __shared__ unsigned short sK[128*128];   // Kd = k * dec^-s ; reused for P
  int bid = blockIdx.x;
  int bh = bid >> 4, c = bid & 15, b = bh >> 4, h = bh & 15;
  int tid = threadIdx.x, w = tid >> 6, lane = tid & 63;
  float dec = 1.f - exp2f(-5.f - (float)h);
  float l2d = log2f(dec);

  #pragma unroll
  for(int p=0;p<8;++p){
    int t = p*16 + (tid>>4);
    long row = (long)(b*N_ + c*CH_ + t) * NCAT_ + h*128 + (tid&15)*8;
    short8 qv = *(const short8*)(Y + row);          // q section
    short8 kv = *(const short8*)(Y + row + 2048);   // k section
    float fq = exp2f((float)t * l2d);
    float fk = exp2f(-(float)t * l2d);
    short8 qs, ks;
    #pragma unroll
    for(int u=0;u<8;++u){
      qs[u] = (short)f2bf(bf2f((unsigned short)qv[u]) * fq);
      ks[u] = (short)f2bf(bf2f((unsigned short)kv[u]) * fk);
    }
    int ad = t*256 + (((tid&15)*16) ^ ((t&7)<<4));
    *(short8*)((char*)sQ + ad) = qs;
    *(short8*)((char*)sK + ad) = ks;
  }
  __syncthreads();

  floatx4 acc[2][8] = {};
  // QK^T (already includes dec^{t-s})
  #pragma unroll
  for(int kk=0;kk<4;++kk){
    int cb = (kk<<6) + ((lane>>4)<<4);
    short8 af[2], bfr[8];
    #pragma unroll
    for(int i=0;i<2;++i){ int t = w*32 + (i<<4) + (lane&15); af[i] = *(const short8*)((const char*)sQ + t*256 + (cb ^ ((t&7)<<4))); }
    #pragma unroll
    for(int j=0;j<8;++j){ int s = (j<<4) + (lane&15); bfr[j] = *(const short8*)((const char*)sK + s*256 + (cb ^ ((s&7)<<4))); }
    #pragma unroll
    for(int i=0;i<2;++i)
      #pragma unroll
      for(int j=0;j<8;++j)
        acc[i][j] = __builtin_amdgcn_mfma_f32_16x16x32_bf16(af[i], bfr[j], acc[i][j], 0,0,0);
  }
  __syncthreads();   // all waves done reading sK

  // causal mask, write P (bf16) into sK
  #pragma unroll
  for(int i=0;i<2;++i)
    #pragma unroll
    for(int j=0;j<8;++j)
      #pragma unroll
      for(int r=0;r<4;++r){
        int t = w*32 + (i<<4) + ((lane>>4)<<2) + r;
        int s = (j<<4) + (lane&15);
        float v = (s <= t) ? acc[i][j][r] : 0.f;
        *(unsigned short*)((char*)sK + t*256 + ((s*2) ^ ((t&7)<<4))) = f2bf(v);
      }
  __syncthreads();

  #pragma unroll
  for(int i=0;i<2;++i)
    #pragma unroll
    for(int j=0;j<8;++j)
      #pragma unroll
      for(int u=0;u<4;++u) acc[i][j][u] = 0.f;

  // ret = P @ V
  const unsigned short* Vb = Vt + (long)bh*128*N_ + c*CH_;
  #pragma unroll
  for(int kk=0;kk<4;++kk){
    int cb = (kk<<6) + ((lane>>4)<<4);
    int sg = kk*32 + ((lane>>4)<<3);
    short8 af[2], bfr[8];
    #pragma unroll
    for(int i=0;i<2;++i){ int t = w*32 + (i<<4) + (lane&15); af[i] = *(const short8*)((const char*)sK + t*256 + (cb ^ ((t&7)<<4))); }
    #pragma unroll
    for(int j=0;j<8;++j){ int dv = (j<<4) + (lane&15); bfr[j] = *(const short8*)(Vb + (long)dv*N_ + sg); }
    #pragma unroll
    for(int i=0;i<2;++i)
      #pragma unroll
      for(int j=0;j<8;++j)
        acc[i][j] = __builtin_amdgcn_mfma_f32_16x16x32_bf16(af[i], bfr[j], acc[i][j], 0,0,0);
  }
  // + dec^{t+1} * q @ S_c   (A = Qd*dec, B = Scb[dv][dk])
  const unsigned short* Sb = Scb + ((long)bh*NC_ + c) * 16384;
  #pragma unroll
  for(int kk=0;kk<4;++kk){
    int cb = (kk<<6) + ((lane>>4)<<4);
    int kg = kk*32 + ((lane>>4)<<3);
    short8 af[2], bfr[8];
    #pragma unroll
    for(int i=0;i<2;++i){
      int t = w*32 + (i<<4) + (lane&15);
      short8 qv = *(const short8*)((const char*)sQ + t*256 + (cb ^ ((t&7)<<4)));
      #pragma unroll
      for(int u=0;u<8;++u) af[i][u] = (short)f2bf(bf2f((unsigned short)qv[u]) * dec);
    }
    #pragma unroll
    for(int j=0;j<8;++j){ int dv = (j<<4) + (lane&15); bfr[j] = *(const short8*)(Sb + (long)dv*128 + kg); }
    #pragma unroll
    for(int i=0;i<2;++i)
      #pragma unroll
      for(int j=0;j<8;++j)
        acc[i][j] = __builtin_amdgcn_mfma_f32_16x16x32_bf16(af[i], bfr[j], acc[i][j], 0,0,0);
  }

  // group-norm over DV per row, gate, write bf16
  #pragma unroll
  for(int i=0;i<2;++i){
    #pragma unroll
    for(int r=0;r<4;++r){
      float s1 = 0.f, s2 = 0.f;
      #pragma unroll
      for(int j=0;j<8;++j){ float v = acc[i][j][r]; s1 += v; s2 += v*v; }
      #pragma unroll
      for(int off=1; off<16; off<<=1){ s1 += __shfl_xor(s1, off); s2 += __shfl_xor(s2, off); }
      float mu  = s1 * (1.f/128.f);
      float var = s2 * (1.f/128.f) - mu*mu;
      float inv = rsqrtf(var + 1e-6f);
      int t = w*32 + (i<<4) + ((lane>>4)<<2) + r;
      long mrow = (long)(b*N_ + c*CH_ + t);
      #pragma unroll
      for(int j=0;j<8;++j){
        int dv = (j<<4) + (lane&15);
        float v = (acc[i][j][r] - mu) * inv;
        float g = bf2f(Y[mrow*NCAT_ + 6144 + h*128 + dv]);
        RG[mrow*E_ + h*128 + dv] = f2bf(v * g);
      }
    }
  }
}

// ---------------- launch ----------------
extern "C" void kernel_launch(void* const* d_in, const int* in_sizes, int n_in,
                              void* d_out, int out_size, void* d_ws, size_t ws_size,
                              hipStream_t stream) {
  const float* x  = (const float*)d_in[0];
  const float* Wq = (const float*)d_in[1];
  const float* bq = (const float*)d_in[2];
  const float* Wk = (const float*)d_in[3];
  const float* bk = (const float*)d_in[4];
  const float* Wv = (const float*)d_in[5];
  const float* bv = (const float*)d_in[6];
  const float* Wg = (const float*)d_in[7];
  const float* bg = (const float*)d_in[8];
  const float* Wo = (const float*)d_in[9];
  const float* bo = (const float*)d_in[10];

  char* ws = (char*)d_ws;
  unsigned short* xb   = (unsigned short*)(ws + OFF_XB);
  unsigned short* Wcat = (unsigned short*)(ws + OFF_WCAT);
  unsigned short* Wob  = (unsigned short*)(ws + OFF_WOB);
  float*          bcat = (float*)(ws + OFF_BCAT);
  unsigned short* Y    = (unsigned short*)(ws + OFF_Y);
  unsigned short* Vt   = (unsigned short*)(ws + OFF_VT);
  unsigned short* Scb  = (unsigned short*)(ws + OFF_SCB);
  unsigned short* MS   = (unsigned short*)(ws + OFF_WCAT); // bf16, reuse after GEMM1
  unsigned short* RG   = (unsigned short*)(ws + OFF_XB);   // reuse after GEMM1

  float* outp     = (float*)d_out;
  float* stateOut = outp + (long)M_ * E_;   // 8,388,608

  (void)hipFuncSetAttribute((const void*)k_gemm256,
                            hipFuncAttributeMaxDynamicSharedMemorySize, 131072);
  (void)hipFuncSetAttribute((const void*)k_gemm2,
                            hipFuncAttributeMaxDynamicSharedMemorySize, 98304);

  // fused prep (all casts + bias concat)
  k_castall<<<14340, 256, 0, stream>>>(x, Wq, Wk, Wv, Wg, Wo, bq, bk, bv, bg,
                                       xb, Wcat, Wob, bcat);

  // fused QKVG projection (256^2, 8-phase)
  k_gemm256<<<512, 512, 131072, stream>>>(xb, Wcat, Y, bcat);

  // fused transpose + per-chunk summary (writes Vt + MS bf16)
  k_chunksumT<<<512, 256, 0, stream>>>(Y, Vt, MS);

  // sequential-over-chunks scan (parallel over state elements)
  k_scan<<<512, 256, 0, stream>>>(MS, Scb, stateOut);

  // retention output (masked QK^T @ V + cross term, group-norm, gate)
  k_ret<<<512, 256, 0, stream>>>(Y, Vt, Scb, RG);

  // output projection (256x128 4-phase)
  k_gemm2<<<256, 512, 98304, stream>>>(RG, Wob, outp, bo);
}